// Round 2
// baseline (482.063 us; speedup 1.0000x reference)
//
#include <hip/hip_runtime.h>
#include <hip/hip_fp16.h>
#include <math.h>

#define WG  256
#define EWG 128

typedef _Float16 f16x8 __attribute__((ext_vector_type(8)));
typedef float    f32x4 __attribute__((ext_vector_type(4)));

// scalar tanh-form GELU (fallback kernels)
__device__ __forceinline__ float gelu_f(float x) {
    float u = 0.7978845608028654f * x * fmaf(0.044715f * x, x, 1.0f);
    u = fminf(fmaxf(u, -9.0f), 9.0f);
    const float e = __expf(2.0f * u);
    return 0.5f * x * (1.0f + __fdividef(e - 1.0f, e + 1.0f));
}

// pair GELU: polynomial+clamp in f32, exp/ratio in packed f16.
// 2u computed directly (const-folded 2x); clamped to +-8.4 so exp(2u) <= 4447
// stays in f16 range; tanh(4.2)=1 within ~5e-4. Max |err| vs erf-GELU ~3e-3.
__device__ __forceinline__ __half2 gelu2(float xa, float xb) {
    float ua = 1.5957691216f * xa * fmaf(0.044715f * xa, xa, 1.0f);
    float ub = 1.5957691216f * xb * fmaf(0.044715f * xb, xb, 1.0f);
    ua = fminf(fmaxf(ua, -8.4f), 8.4f);
    ub = fminf(fmaxf(ub, -8.4f), 8.4f);
    const __half2 e   = h2exp(__float22half2_rn(make_float2(ua, ub)));
    const __half2 one = __float2half2_rn(1.0f);
    const __half2 t   = __hmul2(__hsub2(e, one), h2rcp(__hadd2(e, one)));
    const float2  tf  = __half22float2(t);
    return __float22half2_rn(make_float2(0.5f * xa * (1.0f + tf.x),
                                         0.5f * xb * (1.0f + tf.y)));
}

// wave-private LDS fence: drain DS queue + compiler memory barrier
#define WAVE_LDS_FENCE() asm volatile("s_waitcnt lgkmcnt(0)" ::: "memory")

__device__ __forceinline__ void acc_h4(f32x4& s, uint2 r) {
    const __half2 ha = *(const __half2*)&r.x;
    const __half2 hb = *(const __half2*)&r.y;
    const float2 fa = __half22float2(ha);
    const float2 fb = __half22float2(hb);
    s[0] += fa.x; s[1] += fa.y; s[2] += fb.x; s[3] += fb.y;
}

// ---- P0: pack node records (32B) + f16 MFMA weight fragments + zero cnt/stats ----
// packed[n*8]  = {cx,cy,cz,nx, ny,nz,k0,k1}
__global__ __launch_bounds__(256) void pack_kernel(
    const float* __restrict__ coords, const float* __restrict__ normals,
    const float* __restrict__ curv,
    const float* __restrict__ W1, const float* __restrict__ W2,
    const float* __restrict__ W3,
    float* __restrict__ packed, _Float16* __restrict__ wpk,
    float* __restrict__ stats, int* __restrict__ cnt, int N)
{
    const int tid = threadIdx.x;
    for (int n = blockIdx.x * 256 + tid; n < N; n += gridDim.x * 256) {
        const f32x4 lo = {coords[3*n], coords[3*n+1], coords[3*n+2], normals[3*n]};
        const f32x4 hi = {normals[3*n+1], normals[3*n+2], curv[4*n], curv[4*n+1]};
        f32x4* P = (f32x4*)packed;
        P[(size_t)n*2]     = lo;
        P[(size_t)n*2 + 1] = hi;
        cnt[n] = 0;
    }
    if (blockIdx.x == 0) {
        if (tid < 64) stats[tid] = 0.f;
        for (int k = tid; k < 2048; k += 256) {
            const int j = k & 7, col = (k >> 3) & 15, n = (k >> 7) & 3, q = k >> 9;
            wpk[k] = (q == 0) ? (_Float16)W1[j*64 + n*16 + col] : (_Float16)0.f;
        }
        for (int k = tid; k < 2048; k += 256) {
            const int j = k & 7, col = (k >> 3) & 15, q = (k >> 7) & 3,
                      n = (k >> 9) & 1, s = k >> 10;
            wpk[2048 + k] = (_Float16)W2[(s*32 + q*8 + j)*32 + n*16 + col];
        }
        for (int k = tid; k < 512; k += 256) {
            const int j = k & 7, col = (k >> 3) & 15, q = k >> 7;
            wpk[4096 + k] = (_Float16)W3[(q*8 + j)*16 + col];
        }
    }
}

// ---- K1: per-edge MLP via MFMA; 128-thread blocks (2 waves) for residency ----
// mode 2: slot-order ELL — write edge row directly to both endpoints' ELL rows.
// mode 1: ELL slots    — ef16[e] sequential + slots[node*es+pos]=e.
// mode 0: CSR          — ef16[e] sequential + cnt only.
__global__ __launch_bounds__(EWG, 6) void edge_mlp_mfma(
    const float* __restrict__ coords,
    const float* __restrict__ normals,
    const float* __restrict__ curv,
    const int*   __restrict__ eidx,
    const float* __restrict__ W1, const float* __restrict__ b1,
    const float* __restrict__ W2, const float* __restrict__ b2,
    const float* __restrict__ W3, const float* __restrict__ b3,
    __half* __restrict__ ef16, int* __restrict__ cnt,
    int* __restrict__ slots, _Float16* __restrict__ ellA,
    int es, int mode,
    float* __restrict__ stats, int E,
    const float* __restrict__ packed, const _Float16* __restrict__ wpk)
{
    // per-wave staging for a PAIR of 16-edge tiles (32 rows)
    __shared__ __half h1s[2][32][68];   // layer-1 acts; later reused as c3 transpose buf
    __shared__ __half h2s[2][32][36];   // layer-2 acts
    __shared__ float red[2][32];

    const int t    = threadIdx.x;
    const int w    = t >> 6;
    const int lane = t & 63;
    const int quad = lane >> 4;
    const int col  = lane & 15;

    // ---- per-lane edge ids + early atomics ----
    const int e  = blockIdx.x * EWG + w * 64 + lane;
    const bool ev = (e < E);
    const int ec = ev ? e : 0;
    const int r = eidx[ec];
    const int c = eidx[E + ec];

    int pr = 0, qc = 0;
    if (ev) {
        pr = atomicAdd(&cnt[r], 1);
        qc = atomicAdd(&cnt[c], 1);
    }
    const int packR = (ev && pr < es) ? r * es + pr : -1;
    const int packC = (ev && qc < es) ? c * es + qc : -1;

    // ---- weight B-fragments in registers ----
    f16x8 bw1[4];
    f16x8 bw2[2][2];
    f16x8 bw3;
    if (wpk) {
#pragma unroll
        for (int n = 0; n < 4; ++n)
            bw1[n] = *(const f16x8*)(wpk + (((quad*4 + n)*16 + col) << 3));
#pragma unroll
        for (int s = 0; s < 2; ++s)
#pragma unroll
            for (int n = 0; n < 2; ++n)
                bw2[s][n] = *(const f16x8*)(wpk + 2048 +
                                ((((s*2 + n)*4 + quad)*16 + col) << 3));
        bw3 = *(const f16x8*)(wpk + 4096 + ((quad*16 + col) << 3));
    } else {
#pragma unroll
        for (int n = 0; n < 4; ++n) {
#pragma unroll
            for (int j = 0; j < 8; ++j) {
                const int k = quad * 8 + j;
                bw1[n][j] = (k < 8) ? (_Float16)W1[k * 64 + n * 16 + col] : (_Float16)0.f;
            }
        }
#pragma unroll
        for (int s = 0; s < 2; ++s)
#pragma unroll
            for (int n = 0; n < 2; ++n)
#pragma unroll
                for (int j = 0; j < 8; ++j)
                    bw2[s][n][j] = (_Float16)W2[(s * 32 + quad * 8 + j) * 32 + n * 16 + col];
#pragma unroll
        for (int j = 0; j < 8; ++j)
            bw3[j] = (_Float16)W3[(quad * 8 + j) * 16 + col];
    }

    float b1v[4], b2v[2], b3v;
#pragma unroll
    for (int n = 0; n < 4; ++n) b1v[n] = b1[n * 16 + col];
    b2v[0] = b2[col]; b2v[1] = b2[16 + col];
    b3v = b3[col];

    // ---- geometry -> f[8] ----
    float dx, dy, dz, ndot, cr, cc2, cd0, cd1;
    {
        float rx, ry, rz, nrx, nry, nrz, k0r, k1r;
        float cx, cy, cz, ncx, ncy, ncz, k0c, k1c;
        if (packed) {
            const f32x4* P = (const f32x4*)packed;
            const f32x4 pr0 = P[(size_t)r * 2], pr1 = P[(size_t)r * 2 + 1];
            const f32x4 pc0 = P[(size_t)c * 2], pc1 = P[(size_t)c * 2 + 1];
            rx = pr0[0]; ry = pr0[1]; rz = pr0[2]; nrx = pr0[3];
            nry = pr1[0]; nrz = pr1[1]; k0r = pr1[2]; k1r = pr1[3];
            cx = pc0[0]; cy = pc0[1]; cz = pc0[2]; ncx = pc0[3];
            ncy = pc1[0]; ncz = pc1[1]; k0c = pc1[2]; k1c = pc1[3];
        } else {
            rx = coords[3*r]; ry = coords[3*r+1]; rz = coords[3*r+2];
            cx = coords[3*c]; cy = coords[3*c+1]; cz = coords[3*c+2];
            nrx = normals[3*r]; nry = normals[3*r+1]; nrz = normals[3*r+2];
            ncx = normals[3*c]; ncy = normals[3*c+1]; ncz = normals[3*c+2];
            k0r = curv[4*r]; k1r = curv[4*r+1];
            k0c = curv[4*c]; k1c = curv[4*c+1];
        }
        dx = cx - rx; dy = cy - ry; dz = cz - rz;
        ndot = nrx*ncx + nry*ncy + nrz*ncz;
        const float dn   = sqrtf(dx*dx + dy*dy + dz*dz) + 1e-8f;
        const float inv  = 1.0f / dn;
        const float lo = -1.0f + 1e-8f, hi = 1.0f - 1e-8f;
        cr  = fminf(fmaxf((nrx*dx + nry*dy + nrz*dz) * inv, lo), hi);
        cc2 = fminf(fmaxf((ncx*dx + ncy*dy + ncz*dz) * inv, lo), hi);
        cd0 = k0c - k0r;
        cd1 = k1c - k1r;
    }

    // pack f[8] -> 4x half2 words; shuffle packed u32s (half the bpermutes,
    // converts done once per lane instead of per-tile)
    float f[8] = {dx, dy, dz, ndot, cr, cc2, cd0, cd1};
    uint fp[4];
#pragma unroll
    for (int jj = 0; jj < 4; ++jj) {
        const __half2 hh = __float22half2_rn(make_float2(f[2*jj], f[2*jj+1]));
        fp[jj] = *(const uint*)&hh;
    }

    // ---- mode-1 slot stores ----
    if (mode == 1 && ev) {
        if (pr < es) slots[(size_t)r * es + pr] = e;
        if (qc < es) slots[(size_t)c * es + qc] = e;
    }

    const int e0w = blockIdx.x * EWG + w * 64;
    float vsum = 0.f, vsq = 0.f;

#pragma unroll
    for (int p = 0; p < 2; ++p) {
        // ======== phase 1: layer-1 for tiles mt=2p, 2p+1 ========
#pragma unroll
        for (int mtl = 0; mtl < 2; ++mtl) {
            const int mt = 2 * p + mtl;
            union { uint u[4]; f16x8 v; } U;
#pragma unroll
            for (int jj = 0; jj < 4; ++jj) {
                const int sv = __shfl((int)fp[jj], (mt << 4) + col, 64);
                U.u[jj] = (quad == 0) ? (uint)sv : 0u;
            }
            const f16x8 a1 = U.v;
            f32x4 c1[4];
#pragma unroll
            for (int n = 0; n < 4; ++n) {
                f32x4 c0 = {b1v[n], b1v[n], b1v[n], b1v[n]};
                c1[n] = __builtin_amdgcn_mfma_f32_16x16x32_f16(a1, bw1[n], c0, 0, 0, 0);
            }
            // packed GELU over n-pairs (cols np*32+col and np*32+col+16)
#pragma unroll
            for (int np = 0; np < 2; ++np)
#pragma unroll
                for (int rg = 0; rg < 4; ++rg) {
                    const __half2 g = gelu2(c1[2*np][rg], c1[2*np+1][rg]);
                    __half* dst = &h1s[w][mtl*16 + quad*4 + rg][np*32 + col];
                    dst[0]  = __low2half(g);
                    dst[16] = __high2half(g);
                }
        }
        WAVE_LDS_FENCE();

        // ======== phase 2: layer-2 (both tiles, independent chains) ========
        f32x4 c2s[2][2];
#pragma unroll
        for (int mtl = 0; mtl < 2; ++mtl) {
            const f16x8 a2s0 = *(const f16x8*)&h1s[w][mtl*16 + col][quad * 8];
            const f16x8 a2s1 = *(const f16x8*)&h1s[w][mtl*16 + col][32 + quad * 8];
#pragma unroll
            for (int n = 0; n < 2; ++n) {
                f32x4 c0 = {b2v[n], b2v[n], b2v[n], b2v[n]};
                c0 = __builtin_amdgcn_mfma_f32_16x16x32_f16(a2s0, bw2[0][n], c0, 0, 0, 0);
                c2s[mtl][n] = __builtin_amdgcn_mfma_f32_16x16x32_f16(a2s1, bw2[1][n], c0, 0, 0, 0);
            }
        }
#pragma unroll
        for (int mtl = 0; mtl < 2; ++mtl)
#pragma unroll
            for (int rg = 0; rg < 4; ++rg) {
                const __half2 g = gelu2(c2s[mtl][0][rg], c2s[mtl][1][rg]);
                __half* dst = &h2s[w][mtl*16 + quad*4 + rg][col];
                dst[0]  = __low2half(g);
                dst[16] = __high2half(g);
            }
        WAVE_LDS_FENCE();

        // ======== phase 3: layer-3 + output ========
#pragma unroll
        for (int mtl = 0; mtl < 2; ++mtl) {
            const int mt = 2 * p + mtl;
            const f16x8 a3 = *(const f16x8*)&h2s[w][mtl*16 + col][quad * 8];
            f32x4 c0 = {b3v, b3v, b3v, b3v};
            const f32x4 c3 = __builtin_amdgcn_mfma_f32_16x16x32_f16(a3, bw3, c0, 0, 0, 0);

#pragma unroll
            for (int rg = 0; rg < 4; ++rg) {
                const int me = e0w + mt * 16 + quad * 4 + rg;
                if (me < E) { vsum += c3[rg]; vsq += c3[rg] * c3[rg]; }
            }

            if (mode == 2) {
                // transpose staging into (dead) h1s region, cols 0..15
#pragma unroll
                for (int rg = 0; rg < 4; ++rg)
                    h1s[w][mtl*16 + quad*4 + rg][col] = __float2half(c3[rg]);
            } else {
#pragma unroll
                for (int rg = 0; rg < 4; ++rg) {
                    const int me = e0w + mt * 16 + quad * 4 + rg;
                    if (me < E) ef16[(size_t)me * 16 + col] = __float2half(c3[rg]);
                }
            }
        }

        if (mode == 2) {
            WAVE_LDS_FENCE();
            const int j    = lane >> 2;
            const int subl = lane & 3;
#pragma unroll
            for (int mtl = 0; mtl < 2; ++mtl) {
                const int mt = 2 * p + mtl;
                const unsigned long long v =
                    *(const unsigned long long*)&h1s[w][mtl*16 + j][subl * 4];
                const int srcl = (mt << 4) + j;
                const int dR = __shfl(packR, srcl, 64);
                const int dC = __shfl(packC, srcl, 64);
                // nt: streaming stores must not evict the packed node records from L2
                if (dR >= 0) __builtin_nontemporal_store(v,
                        (unsigned long long*)((char*)ellA + (size_t)dR * 32 + subl * 8));
                if (dC >= 0) __builtin_nontemporal_store(v,
                        (unsigned long long*)((char*)ellA + (size_t)dC * 32 + subl * 8));
            }
        }
    }

    vsum += __shfl_xor(vsum, 16, 64);
    vsq  += __shfl_xor(vsq,  16, 64);
    vsum += __shfl_xor(vsum, 32, 64);
    vsq  += __shfl_xor(vsq,  32, 64);
    if (lane < 16) {
        red[w][col]      = vsum;
        red[w][16 + col] = vsq;
    }
    __syncthreads();
    if (t < 32) {
        const float s = red[0][t] + red[1][t];
        atomicAdd(&stats[t], s);
    }
}

// ---- gather for slot-order ELL: sequential per-node rows ----
__global__ __launch_bounds__(WG) void gather_seq_kernel(
    const _Float16* __restrict__ ellA, const int* __restrict__ cnt,
    const float* __restrict__ Wp, const float* __restrict__ bp,
    const float* __restrict__ gE, const float* __restrict__ bE,
    float* __restrict__ stats, float* __restrict__ X,
    int N, float invE, int es)
{
    __shared__ float sWp[256];
    __shared__ f32x4 syv[4][16][4];
    __shared__ float red2[4][32];

    const int t = threadIdx.x;
    sWp[t] = Wp[t];

    const int w    = t >> 6;
    const int lane = t & 63;
    const int g    = lane >> 2;
    const int subl = lane & 3;
    const int c0   = subl * 4;

    float a[4], bb[4], bpv[4];
#pragma unroll
    for (int cc = 0; cc < 4; ++cc) {
        const int ch = c0 + cc;
        const float mean = stats[ch] * invE;
        const float var  = stats[16 + ch] * invE - mean * mean;
        a[cc]  = gE[ch] * rsqrtf(var + 1e-5f);
        bb[cc] = bE[ch] - mean * a[cc];
        bpv[cc] = bp[ch];
    }

    const int node = blockIdx.x * 64 + w * 16 + g;

    f32x4 s = {0.f, 0.f, 0.f, 0.f};
    int len = 0;
    if (node < N) {
        len = cnt[node];
        const int cap = len < es ? len : es;
        const char* base = (const char*)ellA + (size_t)node * es * 32 + subl * 8;
        int i = 0;
        for (; i + 4 <= cap; i += 4) {
            const uint2 r0 = *(const uint2*)(base + (size_t)(i    ) * 32);
            const uint2 r1 = *(const uint2*)(base + (size_t)(i + 1) * 32);
            const uint2 r2 = *(const uint2*)(base + (size_t)(i + 2) * 32);
            const uint2 r3 = *(const uint2*)(base + (size_t)(i + 3) * 32);
            acc_h4(s, r0); acc_h4(s, r1); acc_h4(s, r2); acc_h4(s, r3);
        }
        for (; i < cap; ++i) {
            const uint2 r0 = *(const uint2*)(base + (size_t)i * 32);
            acc_h4(s, r0);
        }
    }

    const float d    = (float)len;
    const float invd = 1.0f / fmaxf(d, 1.0f);
    f32x4 y;
#pragma unroll
    for (int cc = 0; cc < 4; ++cc)
        y[cc] = (a[cc] * s[cc] + bb[cc] * d) * invd;

    syv[w][g][subl] = y;
    __syncthreads();

    const f32x4 y0 = syv[w][g][0];
    const f32x4 y1 = syv[w][g][1];
    const f32x4 y2 = syv[w][g][2];
    const f32x4 y3 = syv[w][g][3];

    const f32x4* sWp4 = (const f32x4*)sWp;
    f32x4 x = {bpv[0], bpv[1], bpv[2], bpv[3]};
#pragma unroll
    for (int j = 0; j < 4; ++j) {
        const f32x4 wj = sWp4[j * 4 + subl];
#pragma unroll
        for (int cc = 0; cc < 4; ++cc) x[cc] += y0[j] * wj[cc];
    }
#pragma unroll
    for (int j = 0; j < 4; ++j) {
        const f32x4 wj = sWp4[(4 + j) * 4 + subl];
#pragma unroll
        for (int cc = 0; cc < 4; ++cc) x[cc] += y1[j] * wj[cc];
    }
#pragma unroll
    for (int j = 0; j < 4; ++j) {
        const f32x4 wj = sWp4[(8 + j) * 4 + subl];
#pragma unroll
        for (int cc = 0; cc < 4; ++cc) x[cc] += y2[j] * wj[cc];
    }
#pragma unroll
    for (int j = 0; j < 4; ++j) {
        const f32x4 wj = sWp4[(12 + j) * 4 + subl];
#pragma unroll
        for (int cc = 0; cc < 4; ++cc) x[cc] += y3[j] * wj[cc];
    }

    if (node < N) {
        *(f32x4*)&X[(size_t)node * 16 + c0] = x;
    } else {
        x = (f32x4){0.f, 0.f, 0.f, 0.f};
    }

    f32x4 vs = x, vq;
#pragma unroll
    for (int cc = 0; cc < 4; ++cc) vq[cc] = x[cc] * x[cc];
#pragma unroll
    for (int off = 4; off <= 32; off <<= 1) {
#pragma unroll
        for (int cc = 0; cc < 4; ++cc) {
            vs[cc] += __shfl_xor(vs[cc], off, 64);
            vq[cc] += __shfl_xor(vq[cc], off, 64);
        }
    }
    if (lane < 4) {
#pragma unroll
        for (int cc = 0; cc < 4; ++cc) {
            red2[w][c0 + cc]      = vs[cc];
            red2[w][16 + c0 + cc] = vq[cc];
        }
    }
    __syncthreads();
    if (t < 32) {
        const float ssum = red2[0][t] + red2[1][t] + red2[2][t] + red2[3][t];
        atomicAdd(&stats[32 + t], ssum);
    }
}

// ---- scan kernels (CSR fallback only) ----
__global__ __launch_bounds__(WG) void scan_blocks_kernel(
    const int* __restrict__ cnt, int* __restrict__ rowptr,
    int* __restrict__ bsum, int N)
{
    __shared__ int sd[WG];
    const int t = threadIdx.x;
    const int i = blockIdx.x * WG + t;
    const int v = (i < N) ? cnt[i] : 0;
    sd[t] = v;
    __syncthreads();
    for (int off = 1; off < WG; off <<= 1) {
        int x = 0;
        if (t >= off) x = sd[t - off];
        __syncthreads();
        sd[t] += x;
        __syncthreads();
    }
    if (i < N) rowptr[i] = sd[t] - v;
    if (t == WG - 1) bsum[blockIdx.x] = sd[t];
}

__global__ __launch_bounds__(512) void scan_top_kernel(
    const int* __restrict__ bsum, int* __restrict__ boff, int nblk)
{
    __shared__ int sd[512];
    const int t = threadIdx.x;
    const int v = (t < nblk) ? bsum[t] : 0;
    sd[t] = v;
    __syncthreads();
    for (int off = 1; off < 512; off <<= 1) {
        int x = 0;
        if (t >= off) x = sd[t - off];
        __syncthreads();
        sd[t] += x;
        __syncthreads();
    }
    if (t < nblk) boff[t] = sd[t] - v;
}

__global__ __launch_bounds__(WG) void scan_add_kernel(
    int* __restrict__ rowptr, int* __restrict__ cursor,
    const int* __restrict__ boff, int N)
{
    const int i = blockIdx.x * WG + threadIdx.x;
    if (i < N) {
        const int v = rowptr[i] + boff[blockIdx.x];
        rowptr[i] = v;
        cursor[i] = v;
    }
}

__global__ __launch_bounds__(WG) void build_kernel(
    const int* __restrict__ eidx, int* __restrict__ cursor,
    int* __restrict__ slots, int E)
{
    const int e = blockIdx.x * WG + threadIdx.x;
    if (e < E) {
        const int r = eidx[e];
        const int c = eidx[E + e];
        const int p = atomicAdd(&cursor[r], 1);
        slots[p] = e;
        const int q = atomicAdd(&cursor[c], 1);
        slots[q] = e;
    }
}

// ---- gather via slots indirection (ELL-slots / CSR fallback) ----
__global__ __launch_bounds__(WG) void gather_kernel(
    const __half* __restrict__ ef16, const int* __restrict__ slots,
    const int* __restrict__ rowptr, const int* __restrict__ cnt,
    const float* __restrict__ Wp, const float* __restrict__ bp,
    const float* __restrict__ gE, const float* __restrict__ bE,
    float* __restrict__ stats, float* __restrict__ X,
    int N, float invE, int es)
{
    __shared__ float sWp[256];
    __shared__ f32x4 syv[4][16][4];
    __shared__ float red2[4][32];

    const int t = threadIdx.x;
    sWp[t] = Wp[t];

    const int w    = t >> 6;
    const int lane = t & 63;
    const int g    = lane >> 2;
    const int subl = lane & 3;
    const int c0   = subl * 4;

    float a[4], bb[4], bpv[4];
#pragma unroll
    for (int cc = 0; cc < 4; ++cc) {
        const int ch = c0 + cc;
        const float mean = stats[ch] * invE;
        const float var  = stats[16 + ch] * invE - mean * mean;
        a[cc]  = gE[ch] * rsqrtf(var + 1e-5f);
        bb[cc] = bE[ch] - mean * a[cc];
        bpv[cc] = bp[ch];
    }

    const int node = blockIdx.x * 64 + w * 16 + g;

    f32x4 s = {0.f, 0.f, 0.f, 0.f};
    int len = 0;
    if (node < N) {
        len = cnt[node];
        const size_t base = (es > 0) ? (size_t)node * (size_t)es : (size_t)rowptr[node];
        const int cap = (es > 0) ? (len < es ? len : es) : len;
        const int* sl = slots + base;
        int i = 0;
        for (; i + 4 <= cap; i += 4) {
            const int e0 = sl[i], e1 = sl[i+1], e2 = sl[i+2], e3 = sl[i+3];
            const uint2 r0 = *(const uint2*)(ef16 + (size_t)e0 * 16 + c0);
            const uint2 r1 = *(const uint2*)(ef16 + (size_t)e1 * 16 + c0);
            const uint2 r2 = *(const uint2*)(ef16 + (size_t)e2 * 16 + c0);
            const uint2 r3 = *(const uint2*)(ef16 + (size_t)e3 * 16 + c0);
            acc_h4(s, r0); acc_h4(s, r1); acc_h4(s, r2); acc_h4(s, r3);
        }
        for (; i < cap; ++i) {
            const uint2 r0 = *(const uint2*)(ef16 + (size_t)sl[i] * 16 + c0);
            acc_h4(s, r0);
        }
    }

    const float d    = (float)len;
    const float invd = 1.0f / fmaxf(d, 1.0f);
    f32x4 y;
#pragma unroll
    for (int cc = 0; cc < 4; ++cc)
        y[cc] = (a[cc] * s[cc] + bb[cc] * d) * invd;

    syv[w][g][subl] = y;
    __syncthreads();

    const f32x4 y0 = syv[w][g][0];
    const f32x4 y1 = syv[w][g][1];
    const f32x4 y2 = syv[w][g][2];
    const f32x4 y3 = syv[w][g][3];

    const f32x4* sWp4 = (const f32x4*)sWp;
    f32x4 x = {bpv[0], bpv[1], bpv[2], bpv[3]};
#pragma unroll
    for (int j = 0; j < 4; ++j) {
        const f32x4 wj = sWp4[j * 4 + subl];
#pragma unroll
        for (int cc = 0; cc < 4; ++cc) x[cc] += y0[j] * wj[cc];
    }
#pragma unroll
    for (int j = 0; j < 4; ++j) {
        const f32x4 wj = sWp4[(4 + j) * 4 + subl];
#pragma unroll
        for (int cc = 0; cc < 4; ++cc) x[cc] += y1[j] * wj[cc];
    }
#pragma unroll
    for (int j = 0; j < 4; ++j) {
        const f32x4 wj = sWp4[(8 + j) * 4 + subl];
#pragma unroll
        for (int cc = 0; cc < 4; ++cc) x[cc] += y2[j] * wj[cc];
    }
#pragma unroll
    for (int j = 0; j < 4; ++j) {
        const f32x4 wj = sWp4[(12 + j) * 4 + subl];
#pragma unroll
        for (int cc = 0; cc < 4; ++cc) x[cc] += y3[j] * wj[cc];
    }

    if (node < N) {
        *(f32x4*)&X[(size_t)node * 16 + c0] = x;
    } else {
        x = (f32x4){0.f, 0.f, 0.f, 0.f};
    }

    f32x4 vs = x, vq;
#pragma unroll
    for (int cc = 0; cc < 4; ++cc) vq[cc] = x[cc] * x[cc];
#pragma unroll
    for (int off = 4; off <= 32; off <<= 1) {
#pragma unroll
        for (int cc = 0; cc < 4; ++cc) {
            vs[cc] += __shfl_xor(vs[cc], off, 64);
            vq[cc] += __shfl_xor(vq[cc], off, 64);
        }
    }
    if (lane < 4) {
#pragma unroll
        for (int cc = 0; cc < 4; ++cc) {
            red2[w][c0 + cc]      = vs[cc];
            red2[w][16 + c0 + cc] = vq[cc];
        }
    }
    __syncthreads();
    if (t < 32) {
        const float ssum = red2[0][t] + red2[1][t] + red2[2][t] + red2[3][t];
        atomicAdd(&stats[32 + t], ssum);
    }
}

// ---- apply node BN (in-place when X == out) ----
__global__ __launch_bounds__(WG) void out_kernel(
    const float* __restrict__ X, const float* __restrict__ stats,
    const float* __restrict__ gN, const float* __restrict__ bN,
    float* __restrict__ out, int total, float invN)
{
    __shared__ float sA[16], sB[16];
    if (threadIdx.x < 16) {
        const int k = threadIdx.x;
        const float mean = stats[32 + k] * invN;
        const float var  = stats[48 + k] * invN - mean * mean;
        const float a    = gN[k] / sqrtf(var + 1e-5f);
        sA[k] = a;
        sB[k] = bN[k] - mean * a;
    }
    __syncthreads();
    const int i = blockIdx.x * WG + threadIdx.x;
    if (i < total) {
        out[i] = sA[i & 15] * X[i] + sB[i & 15];
    }
}

// ============================ LAUNCH ============================

extern "C" void kernel_launch(void* const* d_in, const int* in_sizes, int n_in,
                              void* d_out, int out_size, void* d_ws, size_t ws_size,
                              hipStream_t stream)
{
    const float* coords  = (const float*)d_in[0];
    const float* normals = (const float*)d_in[1];
    const float* curv    = (const float*)d_in[2];
    const int*   eidx    = (const int*)d_in[3];
    const float* W1 = (const float*)d_in[4];
    const float* b1 = (const float*)d_in[5];
    const float* W2 = (const float*)d_in[6];
    const float* b2 = (const float*)d_in[7];
    const float* W3 = (const float*)d_in[8];
    const float* b3 = (const float*)d_in[9];
    const float* gE = (const float*)d_in[10];
    const float* bE = (const float*)d_in[11];
    const float* Wp = (const float*)d_in[12];
    const float* bp = (const float*)d_in[13];
    const float* gN = (const float*)d_in[14];
    const float* bN = (const float*)d_in[15];

    const int N = in_sizes[0] / 3;
    const int E = in_sizes[3] / 2;
    const int eblk = (E + EWG - 1) / EWG;
    const int nblk = (N + WG - 1) / WG;
    float* out = (float*)d_out;

    const size_t off_cnt   = 256;
    const size_t cnt_bytes = (((size_t)N * 4) + 255) & ~(size_t)255;
    const size_t ef_bytes  = (size_t)E * 32;

    // ---------- slot-order ELL: stats | cnt | ellA | packed nodes | packed weights ----------
    {
        const int es = 64;
        const size_t ell_bytes = (size_t)N * (size_t)es * 32;
        const size_t need_so   = off_cnt + cnt_bytes + ell_bytes;
        if (ws_size >= need_so) {
            float*    stats = (float*)d_ws;
            int*      cnt   = (int*)((char*)d_ws + off_cnt);
            _Float16* ellA  = (_Float16*)((char*)d_ws + off_cnt + cnt_bytes);

            const size_t off_pk = need_so;                 // 256-aligned
            const size_t off_wp = off_pk + (size_t)N * 32; // 32B-aligned
            const bool   ext    = (ws_size >= off_wp + 9216);
            float*    packed = ext ? (float*)((char*)d_ws + off_pk) : nullptr;
            _Float16* wpk    = ext ? (_Float16*)((char*)d_ws + off_wp) : nullptr;

            if (ext) {
                // pack kernel also zeroes cnt + stats
                pack_kernel<<<dim3((N + 255) / 256), dim3(256), 0, stream>>>(
                    coords, normals, curv, W1, W2, W3, packed, wpk, stats, cnt, N);
            } else {
                hipMemsetAsync(d_ws, 0, off_cnt + (size_t)N * 4, stream);
            }

            edge_mlp_mfma<<<dim3(eblk), dim3(EWG), 0, stream>>>(
                coords, normals, curv, eidx, W1, b1, W2, b2, W3, b3,
                (__half*)nullptr, cnt, (int*)nullptr, ellA, es, /*mode*/2, stats, E,
                packed, wpk);

            gather_seq_kernel<<<dim3((N + 63) / 64), dim3(WG), 0, stream>>>(
                ellA, cnt, Wp, bp, gE, bE, stats, out, N, 1.0f / (float)E, es);

            out_kernel<<<dim3((N * 16 + WG - 1) / WG), dim3(WG), 0, stream>>>(
                out, stats, gN, bN, out, N * 16, 1.0f / (float)N);
            return;
        }
    }

    // ---------- ELL-slots: stats | cnt | slots[N*es] | ef16 ----------
    {
        const size_t off_slots = off_cnt + cnt_bytes;
        int es = 0;
        const int strides[3] = {96, 80, 64};
        for (int si = 0; si < 3; ++si) {
            const size_t need = off_slots + (size_t)N * (size_t)strides[si] * 4 + ef_bytes;
            if (need <= ws_size) { es = strides[si]; break; }
        }
        if (es > 0) {
            float*  stats = (float*)d_ws;
            int*    cnt   = (int*)((char*)d_ws + off_cnt);
            int*    slots = (int*)((char*)d_ws + off_slots);
            __half* ef16  = (__half*)((char*)d_ws + off_slots + (size_t)N * (size_t)es * 4);

            hipMemsetAsync(d_ws, 0, off_cnt + (size_t)N * 4, stream);

            edge_mlp_mfma<<<dim3(eblk), dim3(EWG), 0, stream>>>(
                coords, normals, curv, eidx, W1, b1, W2, b2, W3, b3,
                ef16, cnt, slots, (_Float16*)nullptr, es, /*mode*/1, stats, E,
                nullptr, nullptr);

            gather_kernel<<<dim3((N + 63) / 64), dim3(WG), 0, stream>>>(
                ef16, slots, cnt, cnt, Wp, bp, gE, bE, stats, out,
                N, 1.0f / (float)E, es);

            out_kernel<<<dim3((N * 16 + WG - 1) / WG), dim3(WG), 0, stream>>>(
                out, stats, gN, bN, out, N * 16, 1.0f / (float)N);
            return;
        }
    }

    // ---------- CSR path ----------
    const size_t need_csr = (size_t)(64 + 3 * (size_t)N + 8192 + 2 * (size_t)E) * 4
                          + ef_bytes + 256;
    if (ws_size >= need_csr && nblk <= 4096) {
        float*  stats  = (float*)d_ws;
        int*    cnt    = (int*)(stats + 64);
        int*    rowptr = cnt + N;
        int*    cursor = rowptr + N;
        int*    bsum   = cursor + N;
        int*    boff   = bsum + 4096;
        int*    slots  = boff + 4096;
        __half* ef16   = (__half*)(slots + 2 * (size_t)E);

        hipMemsetAsync(d_ws, 0, (size_t)(64 + N) * 4, stream);

        edge_mlp_mfma<<<dim3(eblk), dim3(EWG), 0, stream>>>(
            coords, normals, curv, eidx, W1, b1, W2, b2, W3, b3,
            ef16, cnt, slots, (_Float16*)nullptr, 0, /*mode*/0, stats, E,
            nullptr, nullptr);

        scan_blocks_kernel<<<dim3(nblk), dim3(WG), 0, stream>>>(cnt, rowptr, bsum, N);
        scan_top_kernel<<<dim3(1), dim3(512), 0, stream>>>(bsum, boff, nblk);
        scan_add_kernel<<<dim3(nblk), dim3(WG), 0, stream>>>(rowptr, cursor, boff, N);
        build_kernel<<<dim3((E + WG - 1) / WG), dim3(WG), 0, stream>>>(eidx, cursor, slots, E);

        gather_kernel<<<dim3((N + 63) / 64), dim3(WG), 0, stream>>>(
            ef16, slots, rowptr, cnt, Wp, bp, gE, bE, stats, out,
            N, 1.0f / (float)E, 0);

        out_kernel<<<dim3((N * 16 + WG - 1) / WG), dim3(WG), 0, stream>>>(
            out, stats, gN, bN, out, N * 16, 1.0f / (float)N);
        return;
    }
}

// Round 3
// 417.764 us; speedup vs baseline: 1.1539x; 1.1539x over previous
//
#include <hip/hip_runtime.h>
#include <hip/hip_fp16.h>
#include <math.h>

#define WG  256
#define EWG 128

typedef _Float16 f16x8 __attribute__((ext_vector_type(8)));
typedef float    f32x4 __attribute__((ext_vector_type(4)));

// scalar tanh-form GELU (fallback kernels)
__device__ __forceinline__ float gelu_f(float x) {
    float u = 0.7978845608028654f * x * fmaf(0.044715f * x, x, 1.0f);
    u = fminf(fmaxf(u, -9.0f), 9.0f);
    const float e = __expf(2.0f * u);
    return 0.5f * x * (1.0f + __fdividef(e - 1.0f, e + 1.0f));
}

// pair GELU: polynomial+clamp in f32, exp/ratio in packed f16.
// 2u computed directly (const-folded 2x); clamped to +-8.4 so exp(2u) <= 4447
// stays in f16 range; tanh(4.2)=1 within ~5e-4. Max |err| vs erf-GELU ~3e-3.
__device__ __forceinline__ __half2 gelu2(float xa, float xb) {
    float ua = 1.5957691216f * xa * fmaf(0.044715f * xa, xa, 1.0f);
    float ub = 1.5957691216f * xb * fmaf(0.044715f * xb, xb, 1.0f);
    ua = fminf(fmaxf(ua, -8.4f), 8.4f);
    ub = fminf(fmaxf(ub, -8.4f), 8.4f);
    const __half2 e   = h2exp(__float22half2_rn(make_float2(ua, ub)));
    const __half2 one = __float2half2_rn(1.0f);
    const __half2 t   = __hmul2(__hsub2(e, one), h2rcp(__hadd2(e, one)));
    const float2  tf  = __half22float2(t);
    return __float22half2_rn(make_float2(0.5f * xa * (1.0f + tf.x),
                                         0.5f * xb * (1.0f + tf.y)));
}

// wave-private LDS fence: drain DS queue + compiler memory barrier
#define WAVE_LDS_FENCE() asm volatile("s_waitcnt lgkmcnt(0)" ::: "memory")

__device__ __forceinline__ void acc_h4(f32x4& s, uint2 r) {
    const __half2 ha = *(const __half2*)&r.x;
    const __half2 hb = *(const __half2*)&r.y;
    const float2 fa = __half22float2(ha);
    const float2 fb = __half22float2(hb);
    s[0] += fa.x; s[1] += fa.y; s[2] += fb.x; s[3] += fb.y;
}

// ---- P0: pack node records (32B) + f16 MFMA weight fragments + zero cnt/stats ----
// packed[n*8]  = {cx,cy,cz,nx, ny,nz,k0,k1}
__global__ __launch_bounds__(256) void pack_kernel(
    const float* __restrict__ coords, const float* __restrict__ normals,
    const float* __restrict__ curv,
    const float* __restrict__ W1, const float* __restrict__ W2,
    const float* __restrict__ W3,
    float* __restrict__ packed, _Float16* __restrict__ wpk,
    float* __restrict__ stats, int* __restrict__ cnt, int N)
{
    const int tid = threadIdx.x;
    for (int n = blockIdx.x * 256 + tid; n < N; n += gridDim.x * 256) {
        const f32x4 lo = {coords[3*n], coords[3*n+1], coords[3*n+2], normals[3*n]};
        const f32x4 hi = {normals[3*n+1], normals[3*n+2], curv[4*n], curv[4*n+1]};
        f32x4* P = (f32x4*)packed;
        P[(size_t)n*2]     = lo;
        P[(size_t)n*2 + 1] = hi;
        cnt[n] = 0;
    }
    if (blockIdx.x == 0) {
        if (tid < 64) stats[tid] = 0.f;
        for (int k = tid; k < 2048; k += 256) {
            const int j = k & 7, col = (k >> 3) & 15, n = (k >> 7) & 3, q = k >> 9;
            wpk[k] = (q == 0) ? (_Float16)W1[j*64 + n*16 + col] : (_Float16)0.f;
        }
        for (int k = tid; k < 2048; k += 256) {
            const int j = k & 7, col = (k >> 3) & 15, q = (k >> 7) & 3,
                      n = (k >> 9) & 1, s = k >> 10;
            wpk[2048 + k] = (_Float16)W2[(s*32 + q*8 + j)*32 + n*16 + col];
        }
        for (int k = tid; k < 512; k += 256) {
            const int j = k & 7, col = (k >> 3) & 15, q = k >> 7;
            wpk[4096 + k] = (_Float16)W3[(q*8 + j)*16 + col];
        }
    }
}

// ---- K1: per-edge MLP via MFMA; 128-thread blocks (2 waves) for residency ----
// __launch_bounds__(128, 4): VGPR cap 128 (NOT 6 -> that forced 40 VGPRs and
// massive scratch spills in R2: FETCH +341MB, WRITE +397MB). LDS 13824B caps
// residency at 11 blocks/CU; expect >=8 resident.
// mode 2: slot-order ELL — write edge row directly to both endpoints' ELL rows.
// mode 1: ELL slots    — ef16[e] sequential + slots[node*es+pos]=e.
// mode 0: CSR          — ef16[e] sequential + cnt only.
__global__ __launch_bounds__(EWG, 4) void edge_mlp_mfma(
    const float* __restrict__ coords,
    const float* __restrict__ normals,
    const float* __restrict__ curv,
    const int*   __restrict__ eidx,
    const float* __restrict__ W1, const float* __restrict__ b1,
    const float* __restrict__ W2, const float* __restrict__ b2,
    const float* __restrict__ W3, const float* __restrict__ b3,
    __half* __restrict__ ef16, int* __restrict__ cnt,
    int* __restrict__ slots, _Float16* __restrict__ ellA,
    int es, int mode,
    float* __restrict__ stats, int E,
    const float* __restrict__ packed, const _Float16* __restrict__ wpk)
{
    // per-wave staging for a PAIR of 16-edge tiles (32 rows)
    __shared__ __half h1s[2][32][68];   // layer-1 acts; later reused as c3 transpose buf
    __shared__ __half h2s[2][32][36];   // layer-2 acts
    __shared__ float red[2][32];

    const int t    = threadIdx.x;
    const int w    = t >> 6;
    const int lane = t & 63;
    const int quad = lane >> 4;
    const int col  = lane & 15;

    // ---- per-lane edge ids + early atomics ----
    const int e  = blockIdx.x * EWG + w * 64 + lane;
    const bool ev = (e < E);
    const int ec = ev ? e : 0;
    const int r = eidx[ec];
    const int c = eidx[E + ec];

    int pr = 0, qc = 0;
    if (ev) {
        pr = atomicAdd(&cnt[r], 1);
        qc = atomicAdd(&cnt[c], 1);
    }
    const int packR = (ev && pr < es) ? r * es + pr : -1;
    const int packC = (ev && qc < es) ? c * es + qc : -1;

    // ---- weight B-fragments in registers ----
    f16x8 bw1[4];
    f16x8 bw2[2][2];
    f16x8 bw3;
    if (wpk) {
#pragma unroll
        for (int n = 0; n < 4; ++n)
            bw1[n] = *(const f16x8*)(wpk + (((quad*4 + n)*16 + col) << 3));
#pragma unroll
        for (int s = 0; s < 2; ++s)
#pragma unroll
            for (int n = 0; n < 2; ++n)
                bw2[s][n] = *(const f16x8*)(wpk + 2048 +
                                ((((s*2 + n)*4 + quad)*16 + col) << 3));
        bw3 = *(const f16x8*)(wpk + 4096 + ((quad*16 + col) << 3));
    } else {
#pragma unroll
        for (int n = 0; n < 4; ++n) {
#pragma unroll
            for (int j = 0; j < 8; ++j) {
                const int k = quad * 8 + j;
                bw1[n][j] = (k < 8) ? (_Float16)W1[k * 64 + n * 16 + col] : (_Float16)0.f;
            }
        }
#pragma unroll
        for (int s = 0; s < 2; ++s)
#pragma unroll
            for (int n = 0; n < 2; ++n)
#pragma unroll
                for (int j = 0; j < 8; ++j)
                    bw2[s][n][j] = (_Float16)W2[(s * 32 + quad * 8 + j) * 32 + n * 16 + col];
#pragma unroll
        for (int j = 0; j < 8; ++j)
            bw3[j] = (_Float16)W3[(quad * 8 + j) * 16 + col];
    }

    float b1v[4], b2v[2], b3v;
#pragma unroll
    for (int n = 0; n < 4; ++n) b1v[n] = b1[n * 16 + col];
    b2v[0] = b2[col]; b2v[1] = b2[16 + col];
    b3v = b3[col];

    // ---- geometry -> f[8] ----
    float dx, dy, dz, ndot, cr, cc2, cd0, cd1;
    {
        float rx, ry, rz, nrx, nry, nrz, k0r, k1r;
        float cx, cy, cz, ncx, ncy, ncz, k0c, k1c;
        if (packed) {
            const f32x4* P = (const f32x4*)packed;
            const f32x4 pr0 = P[(size_t)r * 2], pr1 = P[(size_t)r * 2 + 1];
            const f32x4 pc0 = P[(size_t)c * 2], pc1 = P[(size_t)c * 2 + 1];
            rx = pr0[0]; ry = pr0[1]; rz = pr0[2]; nrx = pr0[3];
            nry = pr1[0]; nrz = pr1[1]; k0r = pr1[2]; k1r = pr1[3];
            cx = pc0[0]; cy = pc0[1]; cz = pc0[2]; ncx = pc0[3];
            ncy = pc1[0]; ncz = pc1[1]; k0c = pc1[2]; k1c = pc1[3];
        } else {
            rx = coords[3*r]; ry = coords[3*r+1]; rz = coords[3*r+2];
            cx = coords[3*c]; cy = coords[3*c+1]; cz = coords[3*c+2];
            nrx = normals[3*r]; nry = normals[3*r+1]; nrz = normals[3*r+2];
            ncx = normals[3*c]; ncy = normals[3*c+1]; ncz = normals[3*c+2];
            k0r = curv[4*r]; k1r = curv[4*r+1];
            k0c = curv[4*c]; k1c = curv[4*c+1];
        }
        dx = cx - rx; dy = cy - ry; dz = cz - rz;
        ndot = nrx*ncx + nry*ncy + nrz*ncz;
        const float dn   = sqrtf(dx*dx + dy*dy + dz*dz) + 1e-8f;
        const float inv  = 1.0f / dn;
        const float lo = -1.0f + 1e-8f, hi = 1.0f - 1e-8f;
        cr  = fminf(fmaxf((nrx*dx + nry*dy + nrz*dz) * inv, lo), hi);
        cc2 = fminf(fmaxf((ncx*dx + ncy*dy + ncz*dz) * inv, lo), hi);
        cd0 = k0c - k0r;
        cd1 = k1c - k1r;
    }

    // pack f[8] -> 4x half2 words; shuffle packed u32s (half the bpermutes,
    // converts done once per lane instead of per-tile)
    float f[8] = {dx, dy, dz, ndot, cr, cc2, cd0, cd1};
    uint fp[4];
#pragma unroll
    for (int jj = 0; jj < 4; ++jj) {
        const __half2 hh = __float22half2_rn(make_float2(f[2*jj], f[2*jj+1]));
        fp[jj] = *(const uint*)&hh;
    }

    // ---- mode-1 slot stores ----
    if (mode == 1 && ev) {
        if (pr < es) slots[(size_t)r * es + pr] = e;
        if (qc < es) slots[(size_t)c * es + qc] = e;
    }

    const int e0w = blockIdx.x * EWG + w * 64;
    float vsum = 0.f, vsq = 0.f;

#pragma unroll
    for (int p = 0; p < 2; ++p) {
        // ======== phase 1: layer-1 for tiles mt=2p, 2p+1 ========
#pragma unroll
        for (int mtl = 0; mtl < 2; ++mtl) {
            const int mt = 2 * p + mtl;
            union { uint u[4]; f16x8 v; } U;
#pragma unroll
            for (int jj = 0; jj < 4; ++jj) {
                const int sv = __shfl((int)fp[jj], (mt << 4) + col, 64);
                U.u[jj] = (quad == 0) ? (uint)sv : 0u;
            }
            const f16x8 a1 = U.v;
            f32x4 c1[4];
#pragma unroll
            for (int n = 0; n < 4; ++n) {
                f32x4 c0 = {b1v[n], b1v[n], b1v[n], b1v[n]};
                c1[n] = __builtin_amdgcn_mfma_f32_16x16x32_f16(a1, bw1[n], c0, 0, 0, 0);
            }
            // packed GELU over n-pairs (cols np*32+col and np*32+col+16)
#pragma unroll
            for (int np = 0; np < 2; ++np)
#pragma unroll
                for (int rg = 0; rg < 4; ++rg) {
                    const __half2 g = gelu2(c1[2*np][rg], c1[2*np+1][rg]);
                    __half* dst = &h1s[w][mtl*16 + quad*4 + rg][np*32 + col];
                    dst[0]  = __low2half(g);
                    dst[16] = __high2half(g);
                }
        }
        WAVE_LDS_FENCE();

        // ======== phase 2: layer-2 (both tiles, independent chains) ========
        f32x4 c2s[2][2];
#pragma unroll
        for (int mtl = 0; mtl < 2; ++mtl) {
            const f16x8 a2s0 = *(const f16x8*)&h1s[w][mtl*16 + col][quad * 8];
            const f16x8 a2s1 = *(const f16x8*)&h1s[w][mtl*16 + col][32 + quad * 8];
#pragma unroll
            for (int n = 0; n < 2; ++n) {
                f32x4 c0 = {b2v[n], b2v[n], b2v[n], b2v[n]};
                c0 = __builtin_amdgcn_mfma_f32_16x16x32_f16(a2s0, bw2[0][n], c0, 0, 0, 0);
                c2s[mtl][n] = __builtin_amdgcn_mfma_f32_16x16x32_f16(a2s1, bw2[1][n], c0, 0, 0, 0);
            }
        }
#pragma unroll
        for (int mtl = 0; mtl < 2; ++mtl)
#pragma unroll
            for (int rg = 0; rg < 4; ++rg) {
                const __half2 g = gelu2(c2s[mtl][0][rg], c2s[mtl][1][rg]);
                __half* dst = &h2s[w][mtl*16 + quad*4 + rg][col];
                dst[0]  = __low2half(g);
                dst[16] = __high2half(g);
            }
        WAVE_LDS_FENCE();

        // ======== phase 3: layer-3 + output ========
#pragma unroll
        for (int mtl = 0; mtl < 2; ++mtl) {
            const int mt = 2 * p + mtl;
            const f16x8 a3 = *(const f16x8*)&h2s[w][mtl*16 + col][quad * 8];
            f32x4 c0 = {b3v, b3v, b3v, b3v};
            const f32x4 c3 = __builtin_amdgcn_mfma_f32_16x16x32_f16(a3, bw3, c0, 0, 0, 0);

#pragma unroll
            for (int rg = 0; rg < 4; ++rg) {
                const int me = e0w + mt * 16 + quad * 4 + rg;
                if (me < E) { vsum += c3[rg]; vsq += c3[rg] * c3[rg]; }
            }

            if (mode == 2) {
                // transpose staging into (dead) h1s region, cols 0..15
#pragma unroll
                for (int rg = 0; rg < 4; ++rg)
                    h1s[w][mtl*16 + quad*4 + rg][col] = __float2half(c3[rg]);
            } else {
#pragma unroll
                for (int rg = 0; rg < 4; ++rg) {
                    const int me = e0w + mt * 16 + quad * 4 + rg;
                    if (me < E) ef16[(size_t)me * 16 + col] = __float2half(c3[rg]);
                }
            }
        }

        if (mode == 2) {
            WAVE_LDS_FENCE();
            const int j    = lane >> 2;
            const int subl = lane & 3;
#pragma unroll
            for (int mtl = 0; mtl < 2; ++mtl) {
                const int mt = 2 * p + mtl;
                const unsigned long long v =
                    *(const unsigned long long*)&h1s[w][mtl*16 + j][subl * 4];
                const int srcl = (mt << 4) + j;
                const int dR = __shfl(packR, srcl, 64);
                const int dC = __shfl(packC, srcl, 64);
                // nt: streaming stores must not evict the packed node records from L2
                if (dR >= 0) __builtin_nontemporal_store(v,
                        (unsigned long long*)((char*)ellA + (size_t)dR * 32 + subl * 8));
                if (dC >= 0) __builtin_nontemporal_store(v,
                        (unsigned long long*)((char*)ellA + (size_t)dC * 32 + subl * 8));
            }
        }
    }

    vsum += __shfl_xor(vsum, 16, 64);
    vsq  += __shfl_xor(vsq,  16, 64);
    vsum += __shfl_xor(vsum, 32, 64);
    vsq  += __shfl_xor(vsq,  32, 64);
    if (lane < 16) {
        red[w][col]      = vsum;
        red[w][16 + col] = vsq;
    }
    __syncthreads();
    if (t < 32) {
        const float s = red[0][t] + red[1][t];
        atomicAdd(&stats[t], s);
    }
}

// ---- gather for slot-order ELL: sequential per-node rows ----
__global__ __launch_bounds__(WG) void gather_seq_kernel(
    const _Float16* __restrict__ ellA, const int* __restrict__ cnt,
    const float* __restrict__ Wp, const float* __restrict__ bp,
    const float* __restrict__ gE, const float* __restrict__ bE,
    float* __restrict__ stats, float* __restrict__ X,
    int N, float invE, int es)
{
    __shared__ float sWp[256];
    __shared__ f32x4 syv[4][16][4];
    __shared__ float red2[4][32];

    const int t = threadIdx.x;
    sWp[t] = Wp[t];

    const int w    = t >> 6;
    const int lane = t & 63;
    const int g    = lane >> 2;
    const int subl = lane & 3;
    const int c0   = subl * 4;

    float a[4], bb[4], bpv[4];
#pragma unroll
    for (int cc = 0; cc < 4; ++cc) {
        const int ch = c0 + cc;
        const float mean = stats[ch] * invE;
        const float var  = stats[16 + ch] * invE - mean * mean;
        a[cc]  = gE[ch] * rsqrtf(var + 1e-5f);
        bb[cc] = bE[ch] - mean * a[cc];
        bpv[cc] = bp[ch];
    }

    const int node = blockIdx.x * 64 + w * 16 + g;

    f32x4 s = {0.f, 0.f, 0.f, 0.f};
    int len = 0;
    if (node < N) {
        len = cnt[node];
        const int cap = len < es ? len : es;
        const char* base = (const char*)ellA + (size_t)node * es * 32 + subl * 8;
        int i = 0;
        for (; i + 4 <= cap; i += 4) {
            const uint2 r0 = *(const uint2*)(base + (size_t)(i    ) * 32);
            const uint2 r1 = *(const uint2*)(base + (size_t)(i + 1) * 32);
            const uint2 r2 = *(const uint2*)(base + (size_t)(i + 2) * 32);
            const uint2 r3 = *(const uint2*)(base + (size_t)(i + 3) * 32);
            acc_h4(s, r0); acc_h4(s, r1); acc_h4(s, r2); acc_h4(s, r3);
        }
        for (; i < cap; ++i) {
            const uint2 r0 = *(const uint2*)(base + (size_t)i * 32);
            acc_h4(s, r0);
        }
    }

    const float d    = (float)len;
    const float invd = 1.0f / fmaxf(d, 1.0f);
    f32x4 y;
#pragma unroll
    for (int cc = 0; cc < 4; ++cc)
        y[cc] = (a[cc] * s[cc] + bb[cc] * d) * invd;

    syv[w][g][subl] = y;
    __syncthreads();

    const f32x4 y0 = syv[w][g][0];
    const f32x4 y1 = syv[w][g][1];
    const f32x4 y2 = syv[w][g][2];
    const f32x4 y3 = syv[w][g][3];

    const f32x4* sWp4 = (const f32x4*)sWp;
    f32x4 x = {bpv[0], bpv[1], bpv[2], bpv[3]};
#pragma unroll
    for (int j = 0; j < 4; ++j) {
        const f32x4 wj = sWp4[j * 4 + subl];
#pragma unroll
        for (int cc = 0; cc < 4; ++cc) x[cc] += y0[j] * wj[cc];
    }
#pragma unroll
    for (int j = 0; j < 4; ++j) {
        const f32x4 wj = sWp4[(4 + j) * 4 + subl];
#pragma unroll
        for (int cc = 0; cc < 4; ++cc) x[cc] += y1[j] * wj[cc];
    }
#pragma unroll
    for (int j = 0; j < 4; ++j) {
        const f32x4 wj = sWp4[(8 + j) * 4 + subl];
#pragma unroll
        for (int cc = 0; cc < 4; ++cc) x[cc] += y2[j] * wj[cc];
    }
#pragma unroll
    for (int j = 0; j < 4; ++j) {
        const f32x4 wj = sWp4[(12 + j) * 4 + subl];
#pragma unroll
        for (int cc = 0; cc < 4; ++cc) x[cc] += y3[j] * wj[cc];
    }

    if (node < N) {
        *(f32x4*)&X[(size_t)node * 16 + c0] = x;
    } else {
        x = (f32x4){0.f, 0.f, 0.f, 0.f};
    }

    f32x4 vs = x, vq;
#pragma unroll
    for (int cc = 0; cc < 4; ++cc) vq[cc] = x[cc] * x[cc];
#pragma unroll
    for (int off = 4; off <= 32; off <<= 1) {
#pragma unroll
        for (int cc = 0; cc < 4; ++cc) {
            vs[cc] += __shfl_xor(vs[cc], off, 64);
            vq[cc] += __shfl_xor(vq[cc], off, 64);
        }
    }
    if (lane < 4) {
#pragma unroll
        for (int cc = 0; cc < 4; ++cc) {
            red2[w][c0 + cc]      = vs[cc];
            red2[w][16 + c0 + cc] = vq[cc];
        }
    }
    __syncthreads();
    if (t < 32) {
        const float ssum = red2[0][t] + red2[1][t] + red2[2][t] + red2[3][t];
        atomicAdd(&stats[32 + t], ssum);
    }
}

// ---- scan kernels (CSR fallback only) ----
__global__ __launch_bounds__(WG) void scan_blocks_kernel(
    const int* __restrict__ cnt, int* __restrict__ rowptr,
    int* __restrict__ bsum, int N)
{
    __shared__ int sd[WG];
    const int t = threadIdx.x;
    const int i = blockIdx.x * WG + t;
    const int v = (i < N) ? cnt[i] : 0;
    sd[t] = v;
    __syncthreads();
    for (int off = 1; off < WG; off <<= 1) {
        int x = 0;
        if (t >= off) x = sd[t - off];
        __syncthreads();
        sd[t] += x;
        __syncthreads();
    }
    if (i < N) rowptr[i] = sd[t] - v;
    if (t == WG - 1) bsum[blockIdx.x] = sd[t];
}

__global__ __launch_bounds__(512) void scan_top_kernel(
    const int* __restrict__ bsum, int* __restrict__ boff, int nblk)
{
    __shared__ int sd[512];
    const int t = threadIdx.x;
    const int v = (t < nblk) ? bsum[t] : 0;
    sd[t] = v;
    __syncthreads();
    for (int off = 1; off < 512; off <<= 1) {
        int x = 0;
        if (t >= off) x = sd[t - off];
        __syncthreads();
        sd[t] += x;
        __syncthreads();
    }
    if (t < nblk) boff[t] = sd[t] - v;
}

__global__ __launch_bounds__(WG) void scan_add_kernel(
    int* __restrict__ rowptr, int* __restrict__ cursor,
    const int* __restrict__ boff, int N)
{
    const int i = blockIdx.x * WG + threadIdx.x;
    if (i < N) {
        const int v = rowptr[i] + boff[blockIdx.x];
        rowptr[i] = v;
        cursor[i] = v;
    }
}

__global__ __launch_bounds__(WG) void build_kernel(
    const int* __restrict__ eidx, int* __restrict__ cursor,
    int* __restrict__ slots, int E)
{
    const int e = blockIdx.x * WG + threadIdx.x;
    if (e < E) {
        const int r = eidx[e];
        const int c = eidx[E + e];
        const int p = atomicAdd(&cursor[r], 1);
        slots[p] = e;
        const int q = atomicAdd(&cursor[c], 1);
        slots[q] = e;
    }
}

// ---- gather via slots indirection (ELL-slots / CSR fallback) ----
__global__ __launch_bounds__(WG) void gather_kernel(
    const __half* __restrict__ ef16, const int* __restrict__ slots,
    const int* __restrict__ rowptr, const int* __restrict__ cnt,
    const float* __restrict__ Wp, const float* __restrict__ bp,
    const float* __restrict__ gE, const float* __restrict__ bE,
    float* __restrict__ stats, float* __restrict__ X,
    int N, float invE, int es)
{
    __shared__ float sWp[256];
    __shared__ f32x4 syv[4][16][4];
    __shared__ float red2[4][32];

    const int t = threadIdx.x;
    sWp[t] = Wp[t];

    const int w    = t >> 6;
    const int lane = t & 63;
    const int g    = lane >> 2;
    const int subl = lane & 3;
    const int c0   = subl * 4;

    float a[4], bb[4], bpv[4];
#pragma unroll
    for (int cc = 0; cc < 4; ++cc) {
        const int ch = c0 + cc;
        const float mean = stats[ch] * invE;
        const float var  = stats[16 + ch] * invE - mean * mean;
        a[cc]  = gE[ch] * rsqrtf(var + 1e-5f);
        bb[cc] = bE[ch] - mean * a[cc];
        bpv[cc] = bp[ch];
    }

    const int node = blockIdx.x * 64 + w * 16 + g;

    f32x4 s = {0.f, 0.f, 0.f, 0.f};
    int len = 0;
    if (node < N) {
        len = cnt[node];
        const size_t base = (es > 0) ? (size_t)node * (size_t)es : (size_t)rowptr[node];
        const int cap = (es > 0) ? (len < es ? len : es) : len;
        const int* sl = slots + base;
        int i = 0;
        for (; i + 4 <= cap; i += 4) {
            const int e0 = sl[i], e1 = sl[i+1], e2 = sl[i+2], e3 = sl[i+3];
            const uint2 r0 = *(const uint2*)(ef16 + (size_t)e0 * 16 + c0);
            const uint2 r1 = *(const uint2*)(ef16 + (size_t)e1 * 16 + c0);
            const uint2 r2 = *(const uint2*)(ef16 + (size_t)e2 * 16 + c0);
            const uint2 r3 = *(const uint2*)(ef16 + (size_t)e3 * 16 + c0);
            acc_h4(s, r0); acc_h4(s, r1); acc_h4(s, r2); acc_h4(s, r3);
        }
        for (; i < cap; ++i) {
            const uint2 r0 = *(const uint2*)(ef16 + (size_t)sl[i] * 16 + c0);
            acc_h4(s, r0);
        }
    }

    const float d    = (float)len;
    const float invd = 1.0f / fmaxf(d, 1.0f);
    f32x4 y;
#pragma unroll
    for (int cc = 0; cc < 4; ++cc)
        y[cc] = (a[cc] * s[cc] + bb[cc] * d) * invd;

    syv[w][g][subl] = y;
    __syncthreads();

    const f32x4 y0 = syv[w][g][0];
    const f32x4 y1 = syv[w][g][1];
    const f32x4 y2 = syv[w][g][2];
    const f32x4 y3 = syv[w][g][3];

    const f32x4* sWp4 = (const f32x4*)sWp;
    f32x4 x = {bpv[0], bpv[1], bpv[2], bpv[3]};
#pragma unroll
    for (int j = 0; j < 4; ++j) {
        const f32x4 wj = sWp4[j * 4 + subl];
#pragma unroll
        for (int cc = 0; cc < 4; ++cc) x[cc] += y0[j] * wj[cc];
    }
#pragma unroll
    for (int j = 0; j < 4; ++j) {
        const f32x4 wj = sWp4[(4 + j) * 4 + subl];
#pragma unroll
        for (int cc = 0; cc < 4; ++cc) x[cc] += y1[j] * wj[cc];
    }
#pragma unroll
    for (int j = 0; j < 4; ++j) {
        const f32x4 wj = sWp4[(8 + j) * 4 + subl];
#pragma unroll
        for (int cc = 0; cc < 4; ++cc) x[cc] += y2[j] * wj[cc];
    }
#pragma unroll
    for (int j = 0; j < 4; ++j) {
        const f32x4 wj = sWp4[(12 + j) * 4 + subl];
#pragma unroll
        for (int cc = 0; cc < 4; ++cc) x[cc] += y3[j] * wj[cc];
    }

    if (node < N) {
        *(f32x4*)&X[(size_t)node * 16 + c0] = x;
    } else {
        x = (f32x4){0.f, 0.f, 0.f, 0.f};
    }

    f32x4 vs = x, vq;
#pragma unroll
    for (int cc = 0; cc < 4; ++cc) vq[cc] = x[cc] * x[cc];
#pragma unroll
    for (int off = 4; off <= 32; off <<= 1) {
#pragma unroll
        for (int cc = 0; cc < 4; ++cc) {
            vs[cc] += __shfl_xor(vs[cc], off, 64);
            vq[cc] += __shfl_xor(vq[cc], off, 64);
        }
    }
    if (lane < 4) {
#pragma unroll
        for (int cc = 0; cc < 4; ++cc) {
            red2[w][c0 + cc]      = vs[cc];
            red2[w][16 + c0 + cc] = vq[cc];
        }
    }
    __syncthreads();
    if (t < 32) {
        const float ssum = red2[0][t] + red2[1][t] + red2[2][t] + red2[3][t];
        atomicAdd(&stats[32 + t], ssum);
    }
}

// ---- apply node BN (in-place when X == out) ----
__global__ __launch_bounds__(WG) void out_kernel(
    const float* __restrict__ X, const float* __restrict__ stats,
    const float* __restrict__ gN, const float* __restrict__ bN,
    float* __restrict__ out, int total, float invN)
{
    __shared__ float sA[16], sB[16];
    if (threadIdx.x < 16) {
        const int k = threadIdx.x;
        const float mean = stats[32 + k] * invN;
        const float var  = stats[48 + k] * invN - mean * mean;
        const float a    = gN[k] / sqrtf(var + 1e-5f);
        sA[k] = a;
        sB[k] = bN[k] - mean * a;
    }
    __syncthreads();
    const int i = blockIdx.x * WG + threadIdx.x;
    if (i < total) {
        out[i] = sA[i & 15] * X[i] + sB[i & 15];
    }
}

// ============================ LAUNCH ============================

extern "C" void kernel_launch(void* const* d_in, const int* in_sizes, int n_in,
                              void* d_out, int out_size, void* d_ws, size_t ws_size,
                              hipStream_t stream)
{
    const float* coords  = (const float*)d_in[0];
    const float* normals = (const float*)d_in[1];
    const float* curv    = (const float*)d_in[2];
    const int*   eidx    = (const int*)d_in[3];
    const float* W1 = (const float*)d_in[4];
    const float* b1 = (const float*)d_in[5];
    const float* W2 = (const float*)d_in[6];
    const float* b2 = (const float*)d_in[7];
    const float* W3 = (const float*)d_in[8];
    const float* b3 = (const float*)d_in[9];
    const float* gE = (const float*)d_in[10];
    const float* bE = (const float*)d_in[11];
    const float* Wp = (const float*)d_in[12];
    const float* bp = (const float*)d_in[13];
    const float* gN = (const float*)d_in[14];
    const float* bN = (const float*)d_in[15];

    const int N = in_sizes[0] / 3;
    const int E = in_sizes[3] / 2;
    const int eblk = (E + EWG - 1) / EWG;
    const int nblk = (N + WG - 1) / WG;
    float* out = (float*)d_out;

    const size_t off_cnt   = 256;
    const size_t cnt_bytes = (((size_t)N * 4) + 255) & ~(size_t)255;
    const size_t ef_bytes  = (size_t)E * 32;

    // ---------- slot-order ELL: stats | cnt | ellA | packed nodes | packed weights ----------
    {
        const int es = 64;
        const size_t ell_bytes = (size_t)N * (size_t)es * 32;
        const size_t need_so   = off_cnt + cnt_bytes + ell_bytes;
        if (ws_size >= need_so) {
            float*    stats = (float*)d_ws;
            int*      cnt   = (int*)((char*)d_ws + off_cnt);
            _Float16* ellA  = (_Float16*)((char*)d_ws + off_cnt + cnt_bytes);

            const size_t off_pk = need_so;                 // 256-aligned
            const size_t off_wp = off_pk + (size_t)N * 32; // 32B-aligned
            const bool   ext    = (ws_size >= off_wp + 9216);
            float*    packed = ext ? (float*)((char*)d_ws + off_pk) : nullptr;
            _Float16* wpk    = ext ? (_Float16*)((char*)d_ws + off_wp) : nullptr;

            if (ext) {
                // pack kernel also zeroes cnt + stats
                pack_kernel<<<dim3((N + 255) / 256), dim3(256), 0, stream>>>(
                    coords, normals, curv, W1, W2, W3, packed, wpk, stats, cnt, N);
            } else {
                hipMemsetAsync(d_ws, 0, off_cnt + (size_t)N * 4, stream);
            }

            edge_mlp_mfma<<<dim3(eblk), dim3(EWG), 0, stream>>>(
                coords, normals, curv, eidx, W1, b1, W2, b2, W3, b3,
                (__half*)nullptr, cnt, (int*)nullptr, ellA, es, /*mode*/2, stats, E,
                packed, wpk);

            gather_seq_kernel<<<dim3((N + 63) / 64), dim3(WG), 0, stream>>>(
                ellA, cnt, Wp, bp, gE, bE, stats, out, N, 1.0f / (float)E, es);

            out_kernel<<<dim3((N * 16 + WG - 1) / WG), dim3(WG), 0, stream>>>(
                out, stats, gN, bN, out, N * 16, 1.0f / (float)N);
            return;
        }
    }

    // ---------- ELL-slots: stats | cnt | slots[N*es] | ef16 ----------
    {
        const size_t off_slots = off_cnt + cnt_bytes;
        int es = 0;
        const int strides[3] = {96, 80, 64};
        for (int si = 0; si < 3; ++si) {
            const size_t need = off_slots + (size_t)N * (size_t)strides[si] * 4 + ef_bytes;
            if (need <= ws_size) { es = strides[si]; break; }
        }
        if (es > 0) {
            float*  stats = (float*)d_ws;
            int*    cnt   = (int*)((char*)d_ws + off_cnt);
            int*    slots = (int*)((char*)d_ws + off_slots);
            __half* ef16  = (__half*)((char*)d_ws + off_slots + (size_t)N * (size_t)es * 4);

            hipMemsetAsync(d_ws, 0, off_cnt + (size_t)N * 4, stream);

            edge_mlp_mfma<<<dim3(eblk), dim3(EWG), 0, stream>>>(
                coords, normals, curv, eidx, W1, b1, W2, b2, W3, b3,
                ef16, cnt, slots, (_Float16*)nullptr, es, /*mode*/1, stats, E,
                nullptr, nullptr);

            gather_kernel<<<dim3((N + 63) / 64), dim3(WG), 0, stream>>>(
                ef16, slots, cnt, cnt, Wp, bp, gE, bE, stats, out,
                N, 1.0f / (float)E, es);

            out_kernel<<<dim3((N * 16 + WG - 1) / WG), dim3(WG), 0, stream>>>(
                out, stats, gN, bN, out, N * 16, 1.0f / (float)N);
            return;
        }
    }

    // ---------- CSR path ----------
    const size_t need_csr = (size_t)(64 + 3 * (size_t)N + 8192 + 2 * (size_t)E) * 4
                          + ef_bytes + 256;
    if (ws_size >= need_csr && nblk <= 4096) {
        float*  stats  = (float*)d_ws;
        int*    cnt    = (int*)(stats + 64);
        int*    rowptr = cnt + N;
        int*    cursor = rowptr + N;
        int*    bsum   = cursor + N;
        int*    boff   = bsum + 4096;
        int*    slots  = boff + 4096;
        __half* ef16   = (__half*)(slots + 2 * (size_t)E);

        hipMemsetAsync(d_ws, 0, (size_t)(64 + N) * 4, stream);

        edge_mlp_mfma<<<dim3(eblk), dim3(EWG), 0, stream>>>(
            coords, normals, curv, eidx, W1, b1, W2, b2, W3, b3,
            ef16, cnt, slots, (_Float16*)nullptr, 0, /*mode*/0, stats, E,
            nullptr, nullptr);

        scan_blocks_kernel<<<dim3(nblk), dim3(WG), 0, stream>>>(cnt, rowptr, bsum, N);
        scan_top_kernel<<<dim3(1), dim3(512), 0, stream>>>(bsum, boff, nblk);
        scan_add_kernel<<<dim3(nblk), dim3(WG), 0, stream>>>(rowptr, cursor, boff, N);
        build_kernel<<<dim3((E + WG - 1) / WG), dim3(WG), 0, stream>>>(eidx, cursor, slots, E);

        gather_kernel<<<dim3((N + 63) / 64), dim3(WG), 0, stream>>>(
            ef16, slots, rowptr, cnt, Wp, bp, gE, bE, stats, out,
            N, 1.0f / (float)E, 0);

        out_kernel<<<dim3((N * 16 + WG - 1) / WG), dim3(WG), 0, stream>>>(
            out, stats, gN, bN, out, N * 16, 1.0f / (float)N);
        return;
    }
}

// Round 4
// 300.564 us; speedup vs baseline: 1.6039x; 1.3899x over previous
//
#include <hip/hip_runtime.h>
#include <hip/hip_fp16.h>
#include <math.h>

#define WG 256

typedef _Float16 f16x8 __attribute__((ext_vector_type(8)));
typedef float    f32x4 __attribute__((ext_vector_type(4)));

// stats layout (floats, at d_ws[0]):
//   [0,256)   edge-stats replicas: rep*32 + {0..15}=sum, {16..31}=sumsq
//   [256,512) node-stats replicas: 256 + rep*32 + {0..15}=sum, {16..31}=sumsq
// 8 replicas, 128B apart -> 8x fewer same-line atomic collisions.

// pair GELU: polynomial+clamp in f32, exp/ratio in packed f16.
// 2u computed directly; clamp +-8.4 so exp(2u) <= 4447 stays in f16 range.
// tanh = 1 - 2/(e+1) (fma form). Max |err| vs erf-GELU ~3e-3.
__device__ __forceinline__ __half2 gelu2(float xa, float xb) {
    float ua = 1.5957691216f * xa * fmaf(0.044715f * xa, xa, 1.0f);
    float ub = 1.5957691216f * xb * fmaf(0.044715f * xb, xb, 1.0f);
    ua = fminf(fmaxf(ua, -8.4f), 8.4f);
    ub = fminf(fmaxf(ub, -8.4f), 8.4f);
    const __half2 e    = h2exp(__float22half2_rn(make_float2(ua, ub)));
    const __half2 one  = __float2half2_rn(1.0f);
    const __half2 neg2 = __float2half2_rn(-2.0f);
    const __half2 t    = __hfma2(neg2, h2rcp(__hadd2(e, one)), one);
    const float2  tf   = __half22float2(t);
    return __float22half2_rn(make_float2(0.5f * xa * (1.0f + tf.x),
                                         0.5f * xb * (1.0f + tf.y)));
}

// wave-private LDS fence: drain DS queue + compiler memory barrier
#define WAVE_LDS_FENCE() asm volatile("s_waitcnt lgkmcnt(0)" ::: "memory")

__device__ __forceinline__ void acc_h4(f32x4& s, uint2 r) {
    const __half2 ha = *(const __half2*)&r.x;
    const __half2 hb = *(const __half2*)&r.y;
    const float2 fa = __half22float2(ha);
    const float2 fb = __half22float2(hb);
    s[0] += fa.x; s[1] += fa.y; s[2] += fb.x; s[3] += fb.y;
}

// ---- P0: pack node records (32B) + f16 MFMA weight fragments + zero cnt/stats ----
// packed[n*8]  = {cx,cy,cz,nx, ny,nz,k0,k1}
__global__ __launch_bounds__(256) void pack_kernel(
    const float* __restrict__ coords, const float* __restrict__ normals,
    const float* __restrict__ curv,
    const float* __restrict__ W1, const float* __restrict__ W2,
    const float* __restrict__ W3,
    float* __restrict__ packed, _Float16* __restrict__ wpk,
    float* __restrict__ stats, int* __restrict__ cnt, int N, int cstr)
{
    const int tid = threadIdx.x;
    for (int n = blockIdx.x * 256 + tid; n < N; n += gridDim.x * 256) {
        const f32x4 lo = {coords[3*n], coords[3*n+1], coords[3*n+2], normals[3*n]};
        const f32x4 hi = {normals[3*n+1], normals[3*n+2], curv[4*n], curv[4*n+1]};
        f32x4* P = (f32x4*)packed;
        P[(size_t)n*2]     = lo;
        P[(size_t)n*2 + 1] = hi;
        cnt[(size_t)n * cstr] = 0;
    }
    if (blockIdx.x == 0) {
        // zero all stats replicas (512 floats)
        for (int k = tid; k < 512; k += 256) stats[k] = 0.f;
        for (int k = tid; k < 2048; k += 256) {
            const int j = k & 7, col = (k >> 3) & 15, n = (k >> 7) & 3, q = k >> 9;
            wpk[k] = (q == 0) ? (_Float16)W1[j*64 + n*16 + col] : (_Float16)0.f;
        }
        for (int k = tid; k < 2048; k += 256) {
            const int j = k & 7, col = (k >> 3) & 15, q = (k >> 7) & 3,
                      n = (k >> 9) & 1, s = k >> 10;
            wpk[2048 + k] = (_Float16)W2[(s*32 + q*8 + j)*32 + n*16 + col];
        }
        for (int k = tid; k < 512; k += 256) {
            const int j = k & 7, col = (k >> 3) & 15, q = k >> 7;
            wpk[4096 + k] = (_Float16)W3[(q*8 + j)*16 + col];
        }
    }
}

// ---- K1: per-edge MLP via MFMA (256 threads / 4 waves: best measured config) ----
// cstr: cnt stride in ints (16 in mode-2 -> one counter per 64B line).
// mode 2: slot-order ELL — write edge row directly to both endpoints' ELL rows.
// mode 1: ELL slots    — ef16[e] sequential + slots[node*es+pos]=e.
// mode 0: CSR          — ef16[e] sequential + cnt only.
__global__ __launch_bounds__(WG, 4) void edge_mlp_mfma(
    const float* __restrict__ coords,
    const float* __restrict__ normals,
    const float* __restrict__ curv,
    const int*   __restrict__ eidx,
    const float* __restrict__ W1, const float* __restrict__ b1,
    const float* __restrict__ W2, const float* __restrict__ b2,
    const float* __restrict__ W3, const float* __restrict__ b3,
    __half* __restrict__ ef16, int* __restrict__ cnt,
    int* __restrict__ slots, _Float16* __restrict__ ellA,
    int es, int mode, int cstr,
    float* __restrict__ stats, int E,
    const float* __restrict__ packed, const _Float16* __restrict__ wpk)
{
    // per-wave staging for a PAIR of 16-edge tiles (32 rows)
    __shared__ __half h1s[4][32][68];   // layer-1 acts; later reused as c3 transpose buf
    __shared__ __half h2s[4][32][36];   // layer-2 acts
    __shared__ float red[4][32];

    const int t    = threadIdx.x;
    const int w    = t >> 6;
    const int lane = t & 63;
    const int quad = lane >> 4;
    const int col  = lane & 15;

    // ---- per-lane edge ids + early atomics ----
    const int e  = blockIdx.x * WG + w * 64 + lane;
    const bool ev = (e < E);
    const int ec = ev ? e : 0;
    const int r = eidx[ec];
    const int c = eidx[E + ec];

    int pr = 0, qc = 0;
    if (ev) {
        pr = atomicAdd(&cnt[(size_t)r * cstr], 1);
        qc = atomicAdd(&cnt[(size_t)c * cstr], 1);
    }
    const int packR = (ev && pr < es) ? r * es + pr : -1;
    const int packC = (ev && qc < es) ? c * es + qc : -1;

    // ---- weight B-fragments in registers ----
    f16x8 bw1[4];
    f16x8 bw2[2][2];
    f16x8 bw3;
    if (wpk) {
#pragma unroll
        for (int n = 0; n < 4; ++n)
            bw1[n] = *(const f16x8*)(wpk + (((quad*4 + n)*16 + col) << 3));
#pragma unroll
        for (int s = 0; s < 2; ++s)
#pragma unroll
            for (int n = 0; n < 2; ++n)
                bw2[s][n] = *(const f16x8*)(wpk + 2048 +
                                ((((s*2 + n)*4 + quad)*16 + col) << 3));
        bw3 = *(const f16x8*)(wpk + 4096 + ((quad*16 + col) << 3));
    } else {
#pragma unroll
        for (int n = 0; n < 4; ++n) {
#pragma unroll
            for (int j = 0; j < 8; ++j) {
                const int k = quad * 8 + j;
                bw1[n][j] = (k < 8) ? (_Float16)W1[k * 64 + n * 16 + col] : (_Float16)0.f;
            }
        }
#pragma unroll
        for (int s = 0; s < 2; ++s)
#pragma unroll
            for (int n = 0; n < 2; ++n)
#pragma unroll
                for (int j = 0; j < 8; ++j)
                    bw2[s][n][j] = (_Float16)W2[(s * 32 + quad * 8 + j) * 32 + n * 16 + col];
#pragma unroll
        for (int j = 0; j < 8; ++j)
            bw3[j] = (_Float16)W3[(quad * 8 + j) * 16 + col];
    }

    float b1v[4], b2v[2], b3v;
#pragma unroll
    for (int n = 0; n < 4; ++n) b1v[n] = b1[n * 16 + col];
    b2v[0] = b2[col]; b2v[1] = b2[16 + col];
    b3v = b3[col];

    // ---- geometry -> f[8] ----
    float dx, dy, dz, ndot, cr, cc2, cd0, cd1;
    {
        float rx, ry, rz, nrx, nry, nrz, k0r, k1r;
        float cx, cy, cz, ncx, ncy, ncz, k0c, k1c;
        if (packed) {
            const f32x4* P = (const f32x4*)packed;
            const f32x4 pr0 = P[(size_t)r * 2], pr1 = P[(size_t)r * 2 + 1];
            const f32x4 pc0 = P[(size_t)c * 2], pc1 = P[(size_t)c * 2 + 1];
            rx = pr0[0]; ry = pr0[1]; rz = pr0[2]; nrx = pr0[3];
            nry = pr1[0]; nrz = pr1[1]; k0r = pr1[2]; k1r = pr1[3];
            cx = pc0[0]; cy = pc0[1]; cz = pc0[2]; ncx = pc0[3];
            ncy = pc1[0]; ncz = pc1[1]; k0c = pc1[2]; k1c = pc1[3];
        } else {
            rx = coords[3*r]; ry = coords[3*r+1]; rz = coords[3*r+2];
            cx = coords[3*c]; cy = coords[3*c+1]; cz = coords[3*c+2];
            nrx = normals[3*r]; nry = normals[3*r+1]; nrz = normals[3*r+2];
            ncx = normals[3*c]; ncy = normals[3*c+1]; ncz = normals[3*c+2];
            k0r = curv[4*r]; k1r = curv[4*r+1];
            k0c = curv[4*c]; k1c = curv[4*c+1];
        }
        dx = cx - rx; dy = cy - ry; dz = cz - rz;
        ndot = nrx*ncx + nry*ncy + nrz*ncz;
        const float dn   = sqrtf(dx*dx + dy*dy + dz*dz) + 1e-8f;
        const float inv  = 1.0f / dn;
        const float lo = -1.0f + 1e-8f, hi = 1.0f - 1e-8f;
        cr  = fminf(fmaxf((nrx*dx + nry*dy + nrz*dz) * inv, lo), hi);
        cc2 = fminf(fmaxf((ncx*dx + ncy*dy + ncz*dz) * inv, lo), hi);
        cd0 = k0c - k0r;
        cd1 = k1c - k1r;
    }

    // pack f[8] -> 4x half2 words; shuffle packed u32s (half the bpermutes,
    // converts done once per lane instead of per-tile)
    float f[8] = {dx, dy, dz, ndot, cr, cc2, cd0, cd1};
    uint fp[4];
#pragma unroll
    for (int jj = 0; jj < 4; ++jj) {
        const __half2 hh = __float22half2_rn(make_float2(f[2*jj], f[2*jj+1]));
        fp[jj] = *(const uint*)&hh;
    }

    // ---- mode-1 slot stores ----
    if (mode == 1 && ev) {
        if (pr < es) slots[(size_t)r * es + pr] = e;
        if (qc < es) slots[(size_t)c * es + qc] = e;
    }

    const int e0w = blockIdx.x * WG + w * 64;
    float vsum = 0.f, vsq = 0.f;

#pragma unroll
    for (int p = 0; p < 2; ++p) {
        // ======== phase 1: layer-1 for tiles mt=2p, 2p+1 ========
#pragma unroll
        for (int mtl = 0; mtl < 2; ++mtl) {
            const int mt = 2 * p + mtl;
            union { uint u[4]; f16x8 v; } U;
#pragma unroll
            for (int jj = 0; jj < 4; ++jj) {
                const int sv = __shfl((int)fp[jj], (mt << 4) + col, 64);
                U.u[jj] = (quad == 0) ? (uint)sv : 0u;
            }
            const f16x8 a1 = U.v;
            f32x4 c1[4];
#pragma unroll
            for (int n = 0; n < 4; ++n) {
                f32x4 c0 = {b1v[n], b1v[n], b1v[n], b1v[n]};
                c1[n] = __builtin_amdgcn_mfma_f32_16x16x32_f16(a1, bw1[n], c0, 0, 0, 0);
            }
            // packed GELU over n-pairs (cols np*32+col and np*32+col+16)
#pragma unroll
            for (int np = 0; np < 2; ++np)
#pragma unroll
                for (int rg = 0; rg < 4; ++rg) {
                    const __half2 g = gelu2(c1[2*np][rg], c1[2*np+1][rg]);
                    __half* dst = &h1s[w][mtl*16 + quad*4 + rg][np*32 + col];
                    dst[0]  = __low2half(g);
                    dst[16] = __high2half(g);
                }
        }
        WAVE_LDS_FENCE();

        // ======== phase 2: layer-2 (both tiles, independent chains) ========
        f32x4 c2s[2][2];
#pragma unroll
        for (int mtl = 0; mtl < 2; ++mtl) {
            const f16x8 a2s0 = *(const f16x8*)&h1s[w][mtl*16 + col][quad * 8];
            const f16x8 a2s1 = *(const f16x8*)&h1s[w][mtl*16 + col][32 + quad * 8];
#pragma unroll
            for (int n = 0; n < 2; ++n) {
                f32x4 c0 = {b2v[n], b2v[n], b2v[n], b2v[n]};
                c0 = __builtin_amdgcn_mfma_f32_16x16x32_f16(a2s0, bw2[0][n], c0, 0, 0, 0);
                c2s[mtl][n] = __builtin_amdgcn_mfma_f32_16x16x32_f16(a2s1, bw2[1][n], c0, 0, 0, 0);
            }
        }
#pragma unroll
        for (int mtl = 0; mtl < 2; ++mtl)
#pragma unroll
            for (int rg = 0; rg < 4; ++rg) {
                const __half2 g = gelu2(c2s[mtl][0][rg], c2s[mtl][1][rg]);
                __half* dst = &h2s[w][mtl*16 + quad*4 + rg][col];
                dst[0]  = __low2half(g);
                dst[16] = __high2half(g);
            }
        WAVE_LDS_FENCE();

        // ======== phase 3: layer-3 + output ========
#pragma unroll
        for (int mtl = 0; mtl < 2; ++mtl) {
            const int mt = 2 * p + mtl;
            const f16x8 a3 = *(const f16x8*)&h2s[w][mtl*16 + col][quad * 8];
            f32x4 c0 = {b3v, b3v, b3v, b3v};
            const f32x4 c3 = __builtin_amdgcn_mfma_f32_16x16x32_f16(a3, bw3, c0, 0, 0, 0);

#pragma unroll
            for (int rg = 0; rg < 4; ++rg) {
                const int me = e0w + mt * 16 + quad * 4 + rg;
                if (me < E) { vsum += c3[rg]; vsq += c3[rg] * c3[rg]; }
            }

            if (mode == 2) {
                // transpose staging into (dead) h1s region, cols 0..15
#pragma unroll
                for (int rg = 0; rg < 4; ++rg)
                    h1s[w][mtl*16 + quad*4 + rg][col] = __float2half(c3[rg]);
            } else {
#pragma unroll
                for (int rg = 0; rg < 4; ++rg) {
                    const int me = e0w + mt * 16 + quad * 4 + rg;
                    if (me < E) ef16[(size_t)me * 16 + col] = __float2half(c3[rg]);
                }
            }
        }

        if (mode == 2) {
            WAVE_LDS_FENCE();
            const int j    = lane >> 2;
            const int subl = lane & 3;
#pragma unroll
            for (int mtl = 0; mtl < 2; ++mtl) {
                const int mt = 2 * p + mtl;
                const unsigned long long v =
                    *(const unsigned long long*)&h1s[w][mtl*16 + j][subl * 4];
                const int srcl = (mt << 4) + j;
                const int dR = __shfl(packR, srcl, 64);
                const int dC = __shfl(packC, srcl, 64);
                // nt: streaming stores must not evict the packed node records from L2
                if (dR >= 0) __builtin_nontemporal_store(v,
                        (unsigned long long*)((char*)ellA + (size_t)dR * 32 + subl * 8));
                if (dC >= 0) __builtin_nontemporal_store(v,
                        (unsigned long long*)((char*)ellA + (size_t)dC * 32 + subl * 8));
            }
        }
    }

    vsum += __shfl_xor(vsum, 16, 64);
    vsq  += __shfl_xor(vsq,  16, 64);
    vsum += __shfl_xor(vsum, 32, 64);
    vsq  += __shfl_xor(vsq,  32, 64);
    if (lane < 16) {
        red[w][col]      = vsum;
        red[w][16 + col] = vsq;
    }
    __syncthreads();
    if (t < 32) {
        const float s = red[0][t] + red[1][t] + red[2][t] + red[3][t];
        // replicated stats: 8 replicas, 128B apart -> 8x less line contention
        atomicAdd(&stats[((blockIdx.x & 7) << 5) + t], s);
    }
}

// ---- gather for slot-order ELL: sequential per-node rows ----
__global__ __launch_bounds__(WG) void gather_seq_kernel(
    const _Float16* __restrict__ ellA, const int* __restrict__ cnt,
    const float* __restrict__ Wp, const float* __restrict__ bp,
    const float* __restrict__ gE, const float* __restrict__ bE,
    float* __restrict__ stats, float* __restrict__ X,
    int N, float invE, int es, int cstr)
{
    __shared__ float sWp[256];
    __shared__ f32x4 syv[4][16][4];
    __shared__ float red2[4][32];

    const int t = threadIdx.x;
    sWp[t] = Wp[t];

    const int w    = t >> 6;
    const int lane = t & 63;
    const int g    = lane >> 2;
    const int subl = lane & 3;
    const int c0   = subl * 4;

    float a[4], bb[4], bpv[4];
#pragma unroll
    for (int cc = 0; cc < 4; ++cc) {
        const int ch = c0 + cc;
        float se = 0.f, sq = 0.f;
#pragma unroll
        for (int rep = 0; rep < 8; ++rep) {
            se += stats[(rep << 5) + ch];
            sq += stats[(rep << 5) + 16 + ch];
        }
        const float mean = se * invE;
        const float var  = sq * invE - mean * mean;
        a[cc]  = gE[ch] * rsqrtf(var + 1e-5f);
        bb[cc] = bE[ch] - mean * a[cc];
        bpv[cc] = bp[ch];
    }

    const int node = blockIdx.x * 64 + w * 16 + g;

    f32x4 s = {0.f, 0.f, 0.f, 0.f};
    int len = 0;
    if (node < N) {
        len = cnt[(size_t)node * cstr];
        const int cap = len < es ? len : es;
        const char* base = (const char*)ellA + (size_t)node * es * 32 + subl * 8;
        int i = 0;
        for (; i + 4 <= cap; i += 4) {
            const uint2 r0 = *(const uint2*)(base + (size_t)(i    ) * 32);
            const uint2 r1 = *(const uint2*)(base + (size_t)(i + 1) * 32);
            const uint2 r2 = *(const uint2*)(base + (size_t)(i + 2) * 32);
            const uint2 r3 = *(const uint2*)(base + (size_t)(i + 3) * 32);
            acc_h4(s, r0); acc_h4(s, r1); acc_h4(s, r2); acc_h4(s, r3);
        }
        for (; i < cap; ++i) {
            const uint2 r0 = *(const uint2*)(base + (size_t)i * 32);
            acc_h4(s, r0);
        }
    }

    const float d    = (float)len;
    const float invd = 1.0f / fmaxf(d, 1.0f);
    f32x4 y;
#pragma unroll
    for (int cc = 0; cc < 4; ++cc)
        y[cc] = (a[cc] * s[cc] + bb[cc] * d) * invd;

    syv[w][g][subl] = y;
    __syncthreads();

    const f32x4 y0 = syv[w][g][0];
    const f32x4 y1 = syv[w][g][1];
    const f32x4 y2 = syv[w][g][2];
    const f32x4 y3 = syv[w][g][3];

    const f32x4* sWp4 = (const f32x4*)sWp;
    f32x4 x = {bpv[0], bpv[1], bpv[2], bpv[3]};
#pragma unroll
    for (int j = 0; j < 4; ++j) {
        const f32x4 wj = sWp4[j * 4 + subl];
#pragma unroll
        for (int cc = 0; cc < 4; ++cc) x[cc] += y0[j] * wj[cc];
    }
#pragma unroll
    for (int j = 0; j < 4; ++j) {
        const f32x4 wj = sWp4[(4 + j) * 4 + subl];
#pragma unroll
        for (int cc = 0; cc < 4; ++cc) x[cc] += y1[j] * wj[cc];
    }
#pragma unroll
    for (int j = 0; j < 4; ++j) {
        const f32x4 wj = sWp4[(8 + j) * 4 + subl];
#pragma unroll
        for (int cc = 0; cc < 4; ++cc) x[cc] += y2[j] * wj[cc];
    }
#pragma unroll
    for (int j = 0; j < 4; ++j) {
        const f32x4 wj = sWp4[(12 + j) * 4 + subl];
#pragma unroll
        for (int cc = 0; cc < 4; ++cc) x[cc] += y3[j] * wj[cc];
    }

    if (node < N) {
        *(f32x4*)&X[(size_t)node * 16 + c0] = x;
    } else {
        x = (f32x4){0.f, 0.f, 0.f, 0.f};
    }

    f32x4 vs = x, vq;
#pragma unroll
    for (int cc = 0; cc < 4; ++cc) vq[cc] = x[cc] * x[cc];
#pragma unroll
    for (int off = 4; off <= 32; off <<= 1) {
#pragma unroll
        for (int cc = 0; cc < 4; ++cc) {
            vs[cc] += __shfl_xor(vs[cc], off, 64);
            vq[cc] += __shfl_xor(vq[cc], off, 64);
        }
    }
    if (lane < 4) {
#pragma unroll
        for (int cc = 0; cc < 4; ++cc) {
            red2[w][c0 + cc]      = vs[cc];
            red2[w][16 + c0 + cc] = vq[cc];
        }
    }
    __syncthreads();
    if (t < 32) {
        const float ssum = red2[0][t] + red2[1][t] + red2[2][t] + red2[3][t];
        atomicAdd(&stats[256 + ((blockIdx.x & 7) << 5) + t], ssum);
    }
}

// ---- scan kernels (CSR fallback only) ----
__global__ __launch_bounds__(WG) void scan_blocks_kernel(
    const int* __restrict__ cnt, int* __restrict__ rowptr,
    int* __restrict__ bsum, int N)
{
    __shared__ int sd[WG];
    const int t = threadIdx.x;
    const int i = blockIdx.x * WG + t;
    const int v = (i < N) ? cnt[i] : 0;
    sd[t] = v;
    __syncthreads();
    for (int off = 1; off < WG; off <<= 1) {
        int x = 0;
        if (t >= off) x = sd[t - off];
        __syncthreads();
        sd[t] += x;
        __syncthreads();
    }
    if (i < N) rowptr[i] = sd[t] - v;
    if (t == WG - 1) bsum[blockIdx.x] = sd[t];
}

__global__ __launch_bounds__(512) void scan_top_kernel(
    const int* __restrict__ bsum, int* __restrict__ boff, int nblk)
{
    __shared__ int sd[512];
    const int t = threadIdx.x;
    const int v = (t < nblk) ? bsum[t] : 0;
    sd[t] = v;
    __syncthreads();
    for (int off = 1; off < 512; off <<= 1) {
        int x = 0;
        if (t >= off) x = sd[t - off];
        __syncthreads();
        sd[t] += x;
        __syncthreads();
    }
    if (t < nblk) boff[t] = sd[t] - v;
}

__global__ __launch_bounds__(WG) void scan_add_kernel(
    int* __restrict__ rowptr, int* __restrict__ cursor,
    const int* __restrict__ boff, int N)
{
    const int i = blockIdx.x * WG + threadIdx.x;
    if (i < N) {
        const int v = rowptr[i] + boff[blockIdx.x];
        rowptr[i] = v;
        cursor[i] = v;
    }
}

__global__ __launch_bounds__(WG) void build_kernel(
    const int* __restrict__ eidx, int* __restrict__ cursor,
    int* __restrict__ slots, int E)
{
    const int e = blockIdx.x * WG + threadIdx.x;
    if (e < E) {
        const int r = eidx[e];
        const int c = eidx[E + e];
        const int p = atomicAdd(&cursor[r], 1);
        slots[p] = e;
        const int q = atomicAdd(&cursor[c], 1);
        slots[q] = e;
    }
}

// ---- gather via slots indirection (ELL-slots / CSR fallback) ----
__global__ __launch_bounds__(WG) void gather_kernel(
    const __half* __restrict__ ef16, const int* __restrict__ slots,
    const int* __restrict__ rowptr, const int* __restrict__ cnt,
    const float* __restrict__ Wp, const float* __restrict__ bp,
    const float* __restrict__ gE, const float* __restrict__ bE,
    float* __restrict__ stats, float* __restrict__ X,
    int N, float invE, int es)
{
    __shared__ float sWp[256];
    __shared__ f32x4 syv[4][16][4];
    __shared__ float red2[4][32];

    const int t = threadIdx.x;
    sWp[t] = Wp[t];

    const int w    = t >> 6;
    const int lane = t & 63;
    const int g    = lane >> 2;
    const int subl = lane & 3;
    const int c0   = subl * 4;

    float a[4], bb[4], bpv[4];
#pragma unroll
    for (int cc = 0; cc < 4; ++cc) {
        const int ch = c0 + cc;
        float se = 0.f, sq = 0.f;
#pragma unroll
        for (int rep = 0; rep < 8; ++rep) {
            se += stats[(rep << 5) + ch];
            sq += stats[(rep << 5) + 16 + ch];
        }
        const float mean = se * invE;
        const float var  = sq * invE - mean * mean;
        a[cc]  = gE[ch] * rsqrtf(var + 1e-5f);
        bb[cc] = bE[ch] - mean * a[cc];
        bpv[cc] = bp[ch];
    }

    const int node = blockIdx.x * 64 + w * 16 + g;

    f32x4 s = {0.f, 0.f, 0.f, 0.f};
    int len = 0;
    if (node < N) {
        len = cnt[node];
        const size_t base = (es > 0) ? (size_t)node * (size_t)es : (size_t)rowptr[node];
        const int cap = (es > 0) ? (len < es ? len : es) : len;
        const int* sl = slots + base;
        int i = 0;
        for (; i + 4 <= cap; i += 4) {
            const int e0 = sl[i], e1 = sl[i+1], e2 = sl[i+2], e3 = sl[i+3];
            const uint2 r0 = *(const uint2*)(ef16 + (size_t)e0 * 16 + c0);
            const uint2 r1 = *(const uint2*)(ef16 + (size_t)e1 * 16 + c0);
            const uint2 r2 = *(const uint2*)(ef16 + (size_t)e2 * 16 + c0);
            const uint2 r3 = *(const uint2*)(ef16 + (size_t)e3 * 16 + c0);
            acc_h4(s, r0); acc_h4(s, r1); acc_h4(s, r2); acc_h4(s, r3);
        }
        for (; i < cap; ++i) {
            const uint2 r0 = *(const uint2*)(ef16 + (size_t)sl[i] * 16 + c0);
            acc_h4(s, r0);
        }
    }

    const float d    = (float)len;
    const float invd = 1.0f / fmaxf(d, 1.0f);
    f32x4 y;
#pragma unroll
    for (int cc = 0; cc < 4; ++cc)
        y[cc] = (a[cc] * s[cc] + bb[cc] * d) * invd;

    syv[w][g][subl] = y;
    __syncthreads();

    const f32x4 y0 = syv[w][g][0];
    const f32x4 y1 = syv[w][g][1];
    const f32x4 y2 = syv[w][g][2];
    const f32x4 y3 = syv[w][g][3];

    const f32x4* sWp4 = (const f32x4*)sWp;
    f32x4 x = {bpv[0], bpv[1], bpv[2], bpv[3]};
#pragma unroll
    for (int j = 0; j < 4; ++j) {
        const f32x4 wj = sWp4[j * 4 + subl];
#pragma unroll
        for (int cc = 0; cc < 4; ++cc) x[cc] += y0[j] * wj[cc];
    }
#pragma unroll
    for (int j = 0; j < 4; ++j) {
        const f32x4 wj = sWp4[(4 + j) * 4 + subl];
#pragma unroll
        for (int cc = 0; cc < 4; ++cc) x[cc] += y1[j] * wj[cc];
    }
#pragma unroll
    for (int j = 0; j < 4; ++j) {
        const f32x4 wj = sWp4[(8 + j) * 4 + subl];
#pragma unroll
        for (int cc = 0; cc < 4; ++cc) x[cc] += y2[j] * wj[cc];
    }
#pragma unroll
    for (int j = 0; j < 4; ++j) {
        const f32x4 wj = sWp4[(12 + j) * 4 + subl];
#pragma unroll
        for (int cc = 0; cc < 4; ++cc) x[cc] += y3[j] * wj[cc];
    }

    if (node < N) {
        *(f32x4*)&X[(size_t)node * 16 + c0] = x;
    } else {
        x = (f32x4){0.f, 0.f, 0.f, 0.f};
    }

    f32x4 vs = x, vq;
#pragma unroll
    for (int cc = 0; cc < 4; ++cc) vq[cc] = x[cc] * x[cc];
#pragma unroll
    for (int off = 4; off <= 32; off <<= 1) {
#pragma unroll
        for (int cc = 0; cc < 4; ++cc) {
            vs[cc] += __shfl_xor(vs[cc], off, 64);
            vq[cc] += __shfl_xor(vq[cc], off, 64);
        }
    }
    if (lane < 4) {
#pragma unroll
        for (int cc = 0; cc < 4; ++cc) {
            red2[w][c0 + cc]      = vs[cc];
            red2[w][16 + c0 + cc] = vq[cc];
        }
    }
    __syncthreads();
    if (t < 32) {
        const float ssum = red2[0][t] + red2[1][t] + red2[2][t] + red2[3][t];
        atomicAdd(&stats[256 + ((blockIdx.x & 7) << 5) + t], ssum);
    }
}

// ---- apply node BN (in-place when X == out) ----
__global__ __launch_bounds__(WG) void out_kernel(
    const float* __restrict__ X, const float* __restrict__ stats,
    const float* __restrict__ gN, const float* __restrict__ bN,
    float* __restrict__ out, int total, float invN)
{
    __shared__ float sA[16], sB[16];
    if (threadIdx.x < 16) {
        const int k = threadIdx.x;
        float se = 0.f, sq = 0.f;
#pragma unroll
        for (int rep = 0; rep < 8; ++rep) {
            se += stats[256 + (rep << 5) + k];
            sq += stats[256 + (rep << 5) + 16 + k];
        }
        const float mean = se * invN;
        const float var  = sq * invN - mean * mean;
        const float a    = gN[k] / sqrtf(var + 1e-5f);
        sA[k] = a;
        sB[k] = bN[k] - mean * a;
    }
    __syncthreads();
    const int i = blockIdx.x * WG + threadIdx.x;
    if (i < total) {
        out[i] = sA[i & 15] * X[i] + sB[i & 15];
    }
}

// ============================ LAUNCH ============================

extern "C" void kernel_launch(void* const* d_in, const int* in_sizes, int n_in,
                              void* d_out, int out_size, void* d_ws, size_t ws_size,
                              hipStream_t stream)
{
    const float* coords  = (const float*)d_in[0];
    const float* normals = (const float*)d_in[1];
    const float* curv    = (const float*)d_in[2];
    const int*   eidx    = (const int*)d_in[3];
    const float* W1 = (const float*)d_in[4];
    const float* b1 = (const float*)d_in[5];
    const float* W2 = (const float*)d_in[6];
    const float* b2 = (const float*)d_in[7];
    const float* W3 = (const float*)d_in[8];
    const float* b3 = (const float*)d_in[9];
    const float* gE = (const float*)d_in[10];
    const float* bE = (const float*)d_in[11];
    const float* Wp = (const float*)d_in[12];
    const float* bp = (const float*)d_in[13];
    const float* gN = (const float*)d_in[14];
    const float* bN = (const float*)d_in[15];

    const int N = in_sizes[0] / 3;
    const int E = in_sizes[3] / 2;
    const int eblk = (E + WG - 1) / WG;
    const int nblk = (N + WG - 1) / WG;
    float* out = (float*)d_out;

    const size_t off_cnt  = 4096;   // stats = 512 floats (2KB) + pad
    const size_t ef_bytes = (size_t)E * 32;

    // ---------- slot-order ELL: stats | cnt(padded) | ellA | packed | weights ----------
    {
        const int es   = 64;
        const int cstr = 16;  // one counter per 64B line
        const size_t cnt_bytes = (((size_t)N * cstr * 4) + 255) & ~(size_t)255;
        const size_t ell_bytes = (size_t)N * (size_t)es * 32;
        const size_t need_so   = off_cnt + cnt_bytes + ell_bytes;
        if (ws_size >= need_so) {
            float*    stats = (float*)d_ws;
            int*      cnt   = (int*)((char*)d_ws + off_cnt);
            _Float16* ellA  = (_Float16*)((char*)d_ws + off_cnt + cnt_bytes);

            const size_t off_pk = need_so;                 // 256-aligned
            const size_t off_wp = off_pk + (size_t)N * 32; // 32B-aligned
            const bool   ext    = (ws_size >= off_wp + 9216);
            float*    packed = ext ? (float*)((char*)d_ws + off_pk) : nullptr;
            _Float16* wpk    = ext ? (_Float16*)((char*)d_ws + off_wp) : nullptr;

            if (ext) {
                // pack kernel also zeroes cnt + stats
                pack_kernel<<<dim3((N + 255) / 256), dim3(256), 0, stream>>>(
                    coords, normals, curv, W1, W2, W3, packed, wpk, stats, cnt, N, cstr);
            } else {
                hipMemsetAsync(d_ws, 0, off_cnt + cnt_bytes, stream);
            }

            edge_mlp_mfma<<<dim3(eblk), dim3(WG), 0, stream>>>(
                coords, normals, curv, eidx, W1, b1, W2, b2, W3, b3,
                (__half*)nullptr, cnt, (int*)nullptr, ellA, es, /*mode*/2, cstr, stats, E,
                packed, wpk);

            gather_seq_kernel<<<dim3((N + 63) / 64), dim3(WG), 0, stream>>>(
                ellA, cnt, Wp, bp, gE, bE, stats, out, N, 1.0f / (float)E, es, cstr);

            out_kernel<<<dim3((N * 16 + WG - 1) / WG), dim3(WG), 0, stream>>>(
                out, stats, gN, bN, out, N * 16, 1.0f / (float)N);
            return;
        }
    }

    // ---------- ELL-slots: stats | cnt | slots[N*es] | ef16 ----------
    {
        const size_t cnt_bytes = (((size_t)N * 4) + 255) & ~(size_t)255;
        const size_t off_slots = off_cnt + cnt_bytes;
        int es = 0;
        const int strides[3] = {96, 80, 64};
        for (int si = 0; si < 3; ++si) {
            const size_t need = off_slots + (size_t)N * (size_t)strides[si] * 4 + ef_bytes;
            if (need <= ws_size) { es = strides[si]; break; }
        }
        if (es > 0) {
            float*  stats = (float*)d_ws;
            int*    cnt   = (int*)((char*)d_ws + off_cnt);
            int*    slots = (int*)((char*)d_ws + off_slots);
            __half* ef16  = (__half*)((char*)d_ws + off_slots + (size_t)N * (size_t)es * 4);

            hipMemsetAsync(d_ws, 0, off_cnt + (size_t)N * 4, stream);

            edge_mlp_mfma<<<dim3(eblk), dim3(WG), 0, stream>>>(
                coords, normals, curv, eidx, W1, b1, W2, b2, W3, b3,
                ef16, cnt, slots, (_Float16*)nullptr, es, /*mode*/1, /*cstr*/1, stats, E,
                nullptr, nullptr);

            gather_kernel<<<dim3((N + 63) / 64), dim3(WG), 0, stream>>>(
                ef16, slots, cnt, cnt, Wp, bp, gE, bE, stats, out,
                N, 1.0f / (float)E, es);

            out_kernel<<<dim3((N * 16 + WG - 1) / WG), dim3(WG), 0, stream>>>(
                out, stats, gN, bN, out, N * 16, 1.0f / (float)N);
            return;
        }
    }

    // ---------- CSR path ----------
    const size_t need_csr = off_cnt + (size_t)(3 * (size_t)N + 8192 + 2 * (size_t)E) * 4
                          + ef_bytes + 256;
    if (ws_size >= need_csr && nblk <= 4096) {
        float*  stats  = (float*)d_ws;
        int*    cnt    = (int*)((char*)d_ws + off_cnt);
        int*    rowptr = cnt + N;
        int*    cursor = rowptr + N;
        int*    bsum   = cursor + N;
        int*    boff   = bsum + 4096;
        int*    slots  = boff + 4096;
        __half* ef16   = (__half*)(slots + 2 * (size_t)E);

        hipMemsetAsync(d_ws, 0, off_cnt + (size_t)N * 4, stream);

        edge_mlp_mfma<<<dim3(eblk), dim3(WG), 0, stream>>>(
            coords, normals, curv, eidx, W1, b1, W2, b2, W3, b3,
            ef16, cnt, slots, (_Float16*)nullptr, 0, /*mode*/0, /*cstr*/1, stats, E,
            nullptr, nullptr);

        scan_blocks_kernel<<<dim3(nblk), dim3(WG), 0, stream>>>(cnt, rowptr, bsum, N);
        scan_top_kernel<<<dim3(1), dim3(512), 0, stream>>>(bsum, boff, nblk);
        scan_add_kernel<<<dim3(nblk), dim3(WG), 0, stream>>>(rowptr, cursor, boff, N);
        build_kernel<<<dim3((E + WG - 1) / WG), dim3(WG), 0, stream>>>(eidx, cursor, slots, E);

        gather_kernel<<<dim3((N + 63) / 64), dim3(WG), 0, stream>>>(
            ef16, slots, rowptr, cnt, Wp, bp, gE, bE, stats, out,
            N, 1.0f / (float)E, 0);

        out_kernel<<<dim3((N * 16 + WG - 1) / WG), dim3(WG), 0, stream>>>(
            out, stats, gN, bN, out, N * 16, 1.0f / (float)N);
        return;
    }
}